// Round 7
// baseline (337.662 us; speedup 1.0000x reference)
//
#include <hip/hip_runtime.h>
#include <hip/hip_bf16.h>

#define N_NODES 50000
#define N_EDGES 800000
#define NHEAD 4
#define DHEAD 64
#define FDIM 256   // NHEAD*DHEAD == in_feats == out_feats
#define SCANB 1024
#define NSCAN ((N_NODES + SCANB - 1) / SCANB)   // 49

typedef __attribute__((ext_vector_type(8))) short bfrag8;   // 8 bf16 (4 VGPRs)
typedef __attribute__((ext_vector_type(4))) float f32x4;    // 4 fp32 acc

// ---------------- bf16 helpers ----------------
__device__ __forceinline__ unsigned f2bf_rne(float x) {
    unsigned u = __float_as_uint(x);
    return (u + 0x7fffu + ((u >> 16) & 1u)) >> 16;
}
__device__ __forceinline__ float bf2f(unsigned u) {
    return __uint_as_float(u << 16);
}

// ---------------- CSR build ----------------
__global__ void degree_kernel(const int* __restrict__ dst, int* __restrict__ cnt, int E) {
    int e = blockIdx.x * 256 + threadIdx.x;
    if (e < E) atomicAdd(&cnt[dst[e]], 1);
}

__global__ __launch_bounds__(1024) void scan1_kernel(const int* __restrict__ cnt,
                                                     int* __restrict__ partial,
                                                     int* __restrict__ bsum, int N) {
    __shared__ int sdata[SCANB];
    int i = blockIdx.x * SCANB + (int)threadIdx.x;
    int v = (i < N) ? cnt[i] : 0;
    sdata[threadIdx.x] = v;
    __syncthreads();
    for (int off = 1; off < SCANB; off <<= 1) {
        int t = (threadIdx.x >= (unsigned)off) ? sdata[threadIdx.x - off] : 0;
        __syncthreads();
        sdata[threadIdx.x] += t;
        __syncthreads();
    }
    if (i < N) partial[i] = sdata[threadIdx.x];
    if (threadIdx.x == SCANB - 1) bsum[blockIdx.x] = sdata[SCANB - 1];
}

__global__ void scan2_kernel(const int* __restrict__ bsum, int* __restrict__ boff, int nb) {
    int lane = threadIdx.x;   // 64 threads
    int v = (lane < nb) ? bsum[lane] : 0;
#pragma unroll
    for (int off = 1; off < 64; off <<= 1) {
        int o = __shfl_up(v, off, 64);
        if (lane >= off) v += o;
    }
    int excl = __shfl_up(v, 1, 64);
    if (lane == 0) excl = 0;
    if (lane < nb) boff[lane] = excl;
}

__global__ __launch_bounds__(1024) void scan3_kernel(const int* __restrict__ partial,
                                                     const int* __restrict__ boff,
                                                     int* __restrict__ rowptr,
                                                     int* __restrict__ cursor, int N) {
    int i = blockIdx.x * SCANB + (int)threadIdx.x;
    if (i < N) {
        int inc = partial[i] + boff[blockIdx.x];
        rowptr[i + 1] = inc;
        if (i + 1 < N) cursor[i + 1] = inc;
    }
    if (i == 0) { rowptr[0] = 0; cursor[0] = 0; }
}

__global__ void scatter_kernel(const int* __restrict__ src, const int* __restrict__ dst,
                               int* __restrict__ cursor, int* __restrict__ srcs, int E) {
    int e = blockIdx.x * 256 + threadIdx.x;
    if (e < E) {
        int pos = atomicAdd(&cursor[dst[e]], 1);
        srcs[pos] = src[e];
    }
}

// ---------------- W split+transpose: B[256][256] fp32 -> Bth/Btl[n][k] bf16 ----------------
__global__ __launch_bounds__(256) void bconv_kernel(const float* __restrict__ B,
                                                    ushort* __restrict__ Bth,
                                                    ushort* __restrict__ Btl) {
    __shared__ ushort th[16][264], tl[16][264];
    int k0 = blockIdx.x * 16;
    int n = threadIdx.x;
#pragma unroll
    for (int k = 0; k < 16; ++k) {
        float v = B[(size_t)(k0 + k) * 256 + n];
        unsigned hb = f2bf_rne(v);
        th[k][n] = (ushort)hb;
        tl[k][n] = (ushort)(__float_as_uint(v - bf2f(hb)) >> 16);
    }
    __syncthreads();
    ushort oh[16], ol[16];
#pragma unroll
    for (int k = 0; k < 16; ++k) { oh[k] = th[k][n]; ol[k] = tl[k][n]; }
#pragma unroll
    for (int q = 0; q < 4; ++q) {
        *reinterpret_cast<ushort4*>(Bth + (size_t)n * 256 + k0 + q * 4) =
            make_ushort4(oh[q*4+0], oh[q*4+1], oh[q*4+2], oh[q*4+3]);
        *reinterpret_cast<ushort4*>(Btl + (size_t)n * 256 + k0 + q * 4) =
            make_ushort4(ol[q*4+0], ol[q*4+1], ol[q*4+2], ol[q*4+3]);
    }
}

// ---------------- GEMM: Cb[M,256](bf16) = A @ (Bh+Bl), split-bf16 MFMA ----------------
// SPLITA=1: A is fp32, split inline during staging (layer 1).
// SPLITA=0: A pre-split hi/lo bf16 (layer 2, produced by agg1).
template <int SPLITA>
__global__ __launch_bounds__(256) void gemm_mfma_kernel(const float* __restrict__ Af,
                                                        const ushort* __restrict__ Ahg,
                                                        const ushort* __restrict__ Alg,
                                                        const ushort* __restrict__ Bth,
                                                        const ushort* __restrict__ Btl,
                                                        ushort* __restrict__ Cb, int M) {
    __shared__ ushort Ah[128][40], Al[128][40];   // [m][k], 80B row stride (bank-spread)
    __shared__ ushort Bh[128][40], Bl[128][40];   // [n][k]
    const int t = threadIdx.x;
    const int lane = t & 63, wave = t >> 6;
    const int wr = wave >> 1, wc = wave & 1;
    const int row0 = blockIdx.x * 128;
    const int col0 = blockIdx.y * 128;

    f32x4 acc[4][4];
#pragma unroll
    for (int i = 0; i < 4; ++i)
#pragma unroll
        for (int j = 0; j < 4; ++j) { acc[i][j].x = 0.f; acc[i][j].y = 0.f; acc[i][j].z = 0.f; acc[i][j].w = 0.f; }

    const int srow = t >> 1;            // 0..127
    const int skoff = (t & 1) * 16;     // 0 or 16
    int arow = row0 + srow; if (arow >= M) arow = M - 1;   // clamp; stores guarded
    const size_t abase = (size_t)arow * 256 + skoff;
    const size_t bbase = (size_t)(col0 + srow) * 256 + skoff;

    float4 af0, af1, af2, af3;          // SPLITA: 16 fp32 of A
    uint4 r0, r1, r2, r3;               // !SPLITA: Ah/Al 16B each
    uint4 r4, r5, r6, r7;               // B hi/lo

#define LOADK(kk)                                                              \
    do {                                                                       \
        if constexpr (SPLITA) {                                                \
            const float4* pa = reinterpret_cast<const float4*>(Af + abase + (kk)); \
            af0 = pa[0]; af1 = pa[1]; af2 = pa[2]; af3 = pa[3];                \
        } else {                                                               \
            r0 = *reinterpret_cast<const uint4*>(Ahg + abase + (kk));          \
            r1 = *reinterpret_cast<const uint4*>(Ahg + abase + (kk) + 8);      \
            r2 = *reinterpret_cast<const uint4*>(Alg + abase + (kk));          \
            r3 = *reinterpret_cast<const uint4*>(Alg + abase + (kk) + 8);      \
        }                                                                      \
        r4 = *reinterpret_cast<const uint4*>(Bth + bbase + (kk));              \
        r5 = *reinterpret_cast<const uint4*>(Bth + bbase + (kk) + 8);          \
        r6 = *reinterpret_cast<const uint4*>(Btl + bbase + (kk));              \
        r7 = *reinterpret_cast<const uint4*>(Btl + bbase + (kk) + 8);          \
    } while (0)

    LOADK(0);
#pragma unroll
    for (int kk = 0; kk < 256; kk += 32) {
        if (kk) __syncthreads();
        if constexpr (SPLITA) {
            float v[16];
            v[0]=af0.x; v[1]=af0.y; v[2]=af0.z; v[3]=af0.w;
            v[4]=af1.x; v[5]=af1.y; v[6]=af1.z; v[7]=af1.w;
            v[8]=af2.x; v[9]=af2.y; v[10]=af2.z; v[11]=af2.w;
            v[12]=af3.x; v[13]=af3.y; v[14]=af3.z; v[15]=af3.w;
            ushort hh[16], ll[16];
#pragma unroll
            for (int q = 0; q < 16; ++q) {
                unsigned hb = f2bf_rne(v[q]);
                hh[q] = (ushort)hb;
                ll[q] = (ushort)(__float_as_uint(v[q] - bf2f(hb)) >> 16);
            }
#pragma unroll
            for (int q = 0; q < 4; ++q) {
                *reinterpret_cast<ushort4*>(&Ah[srow][skoff + q * 4]) =
                    make_ushort4(hh[q*4+0], hh[q*4+1], hh[q*4+2], hh[q*4+3]);
                *reinterpret_cast<ushort4*>(&Al[srow][skoff + q * 4]) =
                    make_ushort4(ll[q*4+0], ll[q*4+1], ll[q*4+2], ll[q*4+3]);
            }
        } else {
            *reinterpret_cast<uint4*>(&Ah[srow][skoff])     = r0;
            *reinterpret_cast<uint4*>(&Ah[srow][skoff + 8]) = r1;
            *reinterpret_cast<uint4*>(&Al[srow][skoff])     = r2;
            *reinterpret_cast<uint4*>(&Al[srow][skoff + 8]) = r3;
        }
        *reinterpret_cast<uint4*>(&Bh[srow][skoff])     = r4;
        *reinterpret_cast<uint4*>(&Bh[srow][skoff + 8]) = r5;
        *reinterpret_cast<uint4*>(&Bl[srow][skoff])     = r6;
        *reinterpret_cast<uint4*>(&Bl[srow][skoff + 8]) = r7;
        __syncthreads();
        if (kk + 32 < 256) LOADK(kk + 32);   // latency hides under MFMA below

        const int kg = (lane >> 4) * 8;
        const int rsel = lane & 15;
        bfrag8 afh[4], afl[4], bfh[4], bfl[4];
#pragma unroll
        for (int i = 0; i < 4; ++i) {
            afh[i] = *reinterpret_cast<const bfrag8*>(&Ah[wr * 64 + i * 16 + rsel][kg]);
            afl[i] = *reinterpret_cast<const bfrag8*>(&Al[wr * 64 + i * 16 + rsel][kg]);
        }
#pragma unroll
        for (int j = 0; j < 4; ++j) {
            bfh[j] = *reinterpret_cast<const bfrag8*>(&Bh[wc * 64 + j * 16 + rsel][kg]);
            bfl[j] = *reinterpret_cast<const bfrag8*>(&Bl[wc * 64 + j * 16 + rsel][kg]);
        }
#pragma unroll
        for (int i = 0; i < 4; ++i)
#pragma unroll
            for (int j = 0; j < 4; ++j) {
                acc[i][j] = __builtin_amdgcn_mfma_f32_16x16x32_bf16(afh[i], bfh[j], acc[i][j], 0, 0, 0);
                acc[i][j] = __builtin_amdgcn_mfma_f32_16x16x32_bf16(afh[i], bfl[j], acc[i][j], 0, 0, 0);
                acc[i][j] = __builtin_amdgcn_mfma_f32_16x16x32_bf16(afl[i], bfh[j], acc[i][j], 0, 0, 0);
            }
    }
#undef LOADK
    const int ccol = lane & 15;
    const int crow = (lane >> 4) * 4;
#pragma unroll
    for (int i = 0; i < 4; ++i) {
#pragma unroll
        for (int r = 0; r < 4; ++r) {
            int row = row0 + wr * 64 + i * 16 + crow + r;
            if (row >= M) continue;
#pragma unroll
            for (int j = 0; j < 4; ++j) {
                int col = col0 + wc * 64 + j * 16 + ccol;
                float val = (r == 0) ? acc[i][j].x : (r == 1) ? acc[i][j].y : (r == 2) ? acc[i][j].z : acc[i][j].w;
                Cb[(size_t)row * 256 + col] = (ushort)f2bf_rne(val);
            }
        }
    }
}

// ---------------- el/er: per-node head dots (bf16 feat) ----------------
__global__ void eler_kernel(const ushort* __restrict__ featb, const float* __restrict__ al,
                            const float* __restrict__ ar, float* __restrict__ el,
                            float* __restrict__ er, int N) {
    int node = blockIdx.x * 4 + (threadIdx.x >> 6);
    if (node >= N) return;
    int lane = threadIdx.x & 63;
    ushort4 fu = *reinterpret_cast<const ushort4*>(featb + (size_t)node * FDIM + lane * 4);
    float f0 = bf2f(fu.x), f1 = bf2f(fu.y), f2 = bf2f(fu.z), f3 = bf2f(fu.w);
    float4 a = *reinterpret_cast<const float4*>(al + lane * 4);
    float4 b = *reinterpret_cast<const float4*>(ar + lane * 4);
    float pl = f0 * a.x + f1 * a.y + f2 * a.z + f3 * a.w;
    float pr = f0 * b.x + f1 * b.y + f2 * b.z + f3 * b.w;
#pragma unroll
    for (int m = 1; m < 16; m <<= 1) {
        pl += __shfl_xor(pl, m, 64);
        pr += __shfl_xor(pr, m, 64);
    }
    if ((lane & 15) == 0) {
        int h = lane >> 4;
        el[node * NHEAD + h] = pl;
        er[node * NHEAD + h] = pr;
    }
}

// ---------------- gather chunk: 16 edges, issue-all-then-consume ----------------
__device__ __forceinline__ void gather_chunk(
        const ushort* __restrict__ featb, const int* __restrict__ srcs,
        int base, int jmax, float wmine, int lane, int head,
        f32x4& accA, f32x4& accB) {
    int sbase = __builtin_amdgcn_readfirstlane(base);   // SGPR -> s_load path
    ushort4 u[16];
    float wj[16];
#pragma unroll
    for (int j = 0; j < 16; ++j) if (j < jmax) {
        int sj = srcs[sbase + j];                        // scalar load (uniform)
        u[j] = *reinterpret_cast<const ushort4*>(featb + (size_t)sj * FDIM + lane * 4);
    }
#pragma unroll
    for (int j = 0; j < 16; ++j) if (j < jmax)
        wj[j] = __shfl(wmine, 4 * j + head, 64);
#pragma unroll
    for (int j = 0; j < 16; ++j) if (j < jmax) {
        const float w = wj[j];
        if (j & 1) {
            accB.x = fmaf(w, bf2f(u[j].x), accB.x);
            accB.y = fmaf(w, bf2f(u[j].y), accB.y);
            accB.z = fmaf(w, bf2f(u[j].z), accB.z);
            accB.w = fmaf(w, bf2f(u[j].w), accB.w);
        } else {
            accA.x = fmaf(w, bf2f(u[j].x), accA.x);
            accA.y = fmaf(w, bf2f(u[j].y), accA.y);
            accA.z = fmaf(w, bf2f(u[j].z), accA.z);
            accA.w = fmaf(w, bf2f(u[j].w), accA.w);
        }
    }
}

// ---------------- fused softmax + aggregation, one wave per node ----------------
// Phase A: stats with (16 edges x 4 heads) on 64 lanes, caching x per chunk (deg<=64).
// Phase B: per chunk, 16 scalar-indexed gathers issued before consumption;
//          weights from cached x, broadcast by shuffle. Deep MLP, no redundant exp.
__global__ __launch_bounds__(256) void agg_kernel(
        const ushort* __restrict__ featb, const float* __restrict__ el,
        const float* __restrict__ er, const int* __restrict__ rowptr,
        const int* __restrict__ srcs,
        const ushort* __restrict__ resid_h, const ushort* __restrict__ resid_l,
        float* __restrict__ outf, ushort* __restrict__ outh, ushort* __restrict__ outl,
        int N) {
    int node = blockIdx.x * 4 + (threadIdx.x >> 6);
    if (node >= N) return;
    int lane = threadIdx.x & 63;
    int h4 = lane & 3;        // head for stats
    int eo = lane >> 2;       // edge slot within 16-chunk
    int head = lane >> 4;     // head for gather (feature layout)
    float erh = er[(size_t)node * NHEAD + h4];
    int beg = rowptr[node], end = rowptr[node + 1];
    int deg = end - beg;

    // ---- phase A: max & denom per head, x cached for chunks 0..3 ----
    float m = -1e30f, ls = 0.f;
    float xs0 = -1e30f, xs1 = -1e30f, xs2 = -1e30f, xs3 = -1e30f;
#define STAT_CHUNK(C, XS)                                                      \
    if ((C) * 16 < deg) {                                                      \
        int p = beg + (C) * 16 + eo;                                           \
        float x = -1e30f;                                                      \
        if (p < end) {                                                         \
            int s = srcs[p];                                                   \
            float t = el[(size_t)s * NHEAD + h4] + erh;                        \
            x = t > 0.f ? t : 0.2f * t;                                        \
        }                                                                      \
        XS = x;                                                                \
        float cm = x;                                                          \
        cm = fmaxf(cm, __shfl_xor(cm, 4, 64));                                 \
        cm = fmaxf(cm, __shfl_xor(cm, 8, 64));                                 \
        cm = fmaxf(cm, __shfl_xor(cm, 16, 64));                                \
        cm = fmaxf(cm, __shfl_xor(cm, 32, 64));                                \
        float mn = fmaxf(m, cm);                                               \
        ls = ls * __expf(m - mn) + __expf(x - mn);                             \
        m = mn;                                                                \
    }
    STAT_CHUNK(0, xs0)
    STAT_CHUNK(1, xs1)
    STAT_CHUNK(2, xs2)
    STAT_CHUNK(3, xs3)
#undef STAT_CHUNK
    for (int c = 4; c * 16 < deg; ++c) {   // rare overflow path (deg > 64)
        int p = beg + c * 16 + eo;
        float x = -1e30f;
        if (p < end) {
            int s = srcs[p];
            float t = el[(size_t)s * NHEAD + h4] + erh;
            x = t > 0.f ? t : 0.2f * t;
        }
        float cm = x;
        cm = fmaxf(cm, __shfl_xor(cm, 4, 64));
        cm = fmaxf(cm, __shfl_xor(cm, 8, 64));
        cm = fmaxf(cm, __shfl_xor(cm, 16, 64));
        cm = fmaxf(cm, __shfl_xor(cm, 32, 64));
        float mn = fmaxf(m, cm);
        ls = ls * __expf(m - mn) + __expf(x - mn);
        m = mn;
    }
    ls += __shfl_xor(ls, 4, 64);
    ls += __shfl_xor(ls, 8, 64);
    ls += __shfl_xor(ls, 16, 64);
    ls += __shfl_xor(ls, 32, 64);
    float dinv = ls > 0.f ? 1.0f / ls : 0.f;

    // ---- phase B: deep-issue weighted gather ----
    f32x4 accA = {0.f, 0.f, 0.f, 0.f}, accB = accA;
#define GATH_CHUNK(C, XS)                                                      \
    if ((C) * 16 < deg) {                                                      \
        int base = beg + (C) * 16;                                             \
        int jmax = end - base; if (jmax > 16) jmax = 16;                       \
        float wmine = __expf((XS) - m) * dinv;                                 \
        gather_chunk(featb, srcs, base, jmax, wmine, lane, head, accA, accB);  \
    }
    GATH_CHUNK(0, xs0)
    GATH_CHUNK(1, xs1)
    GATH_CHUNK(2, xs2)
    GATH_CHUNK(3, xs3)
#undef GATH_CHUNK
    for (int c = 4; c * 16 < deg; ++c) {   // rare overflow path (deg > 64)
        int base = beg + c * 16;
        int p = base + eo;
        float x = -1e30f;
        if (p < end) {
            int s = srcs[p];
            float t = el[(size_t)s * NHEAD + h4] + erh;
            x = t > 0.f ? t : 0.2f * t;
        }
        int jmax = end - base; if (jmax > 16) jmax = 16;
        float wmine = __expf(x - m) * dinv;
        gather_chunk(featb, srcs, base, jmax, wmine, lane, head, accA, accB);
    }
    float4 acc = make_float4(accA.x + accB.x, accA.y + accB.y,
                             accA.z + accB.z, accA.w + accB.w);

    if (resid_h) {
        ushort4 rh = *reinterpret_cast<const ushort4*>(resid_h + (size_t)node * FDIM + lane * 4);
        ushort4 rl = *reinterpret_cast<const ushort4*>(resid_l + (size_t)node * FDIM + lane * 4);
        acc.x += bf2f(rh.x) + bf2f(rl.x);
        acc.y += bf2f(rh.y) + bf2f(rl.y);
        acc.z += bf2f(rh.z) + bf2f(rl.z);
        acc.w += bf2f(rh.w) + bf2f(rl.w);
    }
    acc.x = acc.x > 0.f ? acc.x : expm1f(acc.x);
    acc.y = acc.y > 0.f ? acc.y : expm1f(acc.y);
    acc.z = acc.z > 0.f ? acc.z : expm1f(acc.z);
    acc.w = acc.w > 0.f ? acc.w : expm1f(acc.w);

    if (outf) {
        *reinterpret_cast<float4*>(outf + (size_t)node * FDIM + lane * 4) = acc;
    } else {
        unsigned h0 = f2bf_rne(acc.x), h1 = f2bf_rne(acc.y), h2 = f2bf_rne(acc.z), h3 = f2bf_rne(acc.w);
        *reinterpret_cast<ushort4*>(outh + (size_t)node * FDIM + lane * 4) =
            make_ushort4((ushort)h0, (ushort)h1, (ushort)h2, (ushort)h3);
        *reinterpret_cast<ushort4*>(outl + (size_t)node * FDIM + lane * 4) = make_ushort4(
            (ushort)(__float_as_uint(acc.x - bf2f(h0)) >> 16),
            (ushort)(__float_as_uint(acc.y - bf2f(h1)) >> 16),
            (ushort)(__float_as_uint(acc.z - bf2f(h2)) >> 16),
            (ushort)(__float_as_uint(acc.w - bf2f(h3)) >> 16));
    }
}

// ---------------- launch ----------------
extern "C" void kernel_launch(void* const* d_in, const int* in_sizes, int n_in,
                              void* d_out, int out_size, void* d_ws, size_t ws_size,
                              hipStream_t stream) {
    const float* features = (const float*)d_in[0];
    const int*   src      = (const int*)d_in[1];
    const int*   dst      = (const int*)d_in[2];
    const float* W1       = (const float*)d_in[3];
    const float* al1      = (const float*)d_in[4];
    const float* ar1      = (const float*)d_in[5];
    const float* W2       = (const float*)d_in[6];
    const float* al2      = (const float*)d_in[7];
    const float* ar2      = (const float*)d_in[8];
    float* out = (float*)d_out;

    const int N = N_NODES, E = N_EDGES;

    char* ws = (char*)d_ws;
    size_t off = 0;
    auto alloc = [&](size_t bytes) -> void* {
        void* p = ws + off;
        off = (off + bytes + 255) & ~(size_t)255;
        return p;
    };
    ushort* featb  = (ushort*)alloc((size_t)N * FDIM * 2);
    ushort* Afh    = (ushort*)alloc((size_t)N * FDIM * 2);   // layer-1 output hi (agg1 out)
    ushort* Afl    = (ushort*)alloc((size_t)N * FDIM * 2);   // layer-1 output lo
    float*  el     = (float*)alloc((size_t)N * NHEAD * 4);
    float*  er     = (float*)alloc((size_t)N * NHEAD * 4);
    int*    rowptr = (int*)alloc((size_t)(N + 1) * 4);
    int*    cnt    = (int*)alloc((size_t)N * 4);
    int*    cursor = (int*)alloc((size_t)N * 4);
    int*    partial= (int*)alloc((size_t)N * 4);
    int*    bsum   = (int*)alloc((size_t)NSCAN * 4);
    int*    boff   = (int*)alloc((size_t)NSCAN * 4);
    int*    srcs   = (int*)alloc((size_t)E * 4);
    ushort* Bth    = (ushort*)alloc((size_t)256 * 256 * 2);
    ushort* Btl    = (ushort*)alloc((size_t)256 * 256 * 2);

    const int egrid = (E + 255) / 256;
    const int ngrid4 = (N + 3) / 4;

    // ---- CSR build (by dst) ----
    hipMemsetAsync(cnt, 0, (size_t)N * 4, stream);
    degree_kernel<<<egrid, 256, 0, stream>>>(dst, cnt, E);
    scan1_kernel<<<NSCAN, SCANB, 0, stream>>>(cnt, partial, bsum, N);
    scan2_kernel<<<1, 64, 0, stream>>>(bsum, boff, NSCAN);
    scan3_kernel<<<NSCAN, SCANB, 0, stream>>>(partial, boff, rowptr, cursor, N);
    scatter_kernel<<<egrid, 256, 0, stream>>>(src, dst, cursor, srcs, E);

    dim3 ggrid((N + 127) / 128, 2);

    // ---- layer 1 (A = fp32 features, split inline in GEMM) ----
    bconv_kernel<<<16, 256, 0, stream>>>(W1, Bth, Btl);
    gemm_mfma_kernel<1><<<ggrid, 256, 0, stream>>>(features, nullptr, nullptr, Bth, Btl, featb, N);
    eler_kernel<<<ngrid4, 256, 0, stream>>>(featb, al1, ar1, el, er, N);
    agg_kernel<<<ngrid4, 256, 0, stream>>>(featb, el, er, rowptr, srcs,
                                           nullptr, nullptr, nullptr, Afh, Afl, N);

    // ---- layer 2 (A = layer-1 output pre-split; residual = hi+lo) ----
    bconv_kernel<<<16, 256, 0, stream>>>(W2, Bth, Btl);
    gemm_mfma_kernel<0><<<ggrid, 256, 0, stream>>>(nullptr, Afh, Afl, Bth, Btl, featb, N);
    eler_kernel<<<ngrid4, 256, 0, stream>>>(featb, al2, ar2, el, er, N);
    agg_kernel<<<ngrid4, 256, 0, stream>>>(featb, el, er, rowptr, srcs,
                                           Afh, Afl, out, nullptr, nullptr, N);
}

// Round 8
// 321.640 us; speedup vs baseline: 1.0498x; 1.0498x over previous
//
#include <hip/hip_runtime.h>
#include <hip/hip_bf16.h>

#define N_NODES 50000
#define N_EDGES 800000
#define NHEAD 4
#define DHEAD 64
#define FDIM 256   // NHEAD*DHEAD == in_feats == out_feats
#define SCANB 1024
#define NSCAN ((N_NODES + SCANB - 1) / SCANB)   // 49

typedef __attribute__((ext_vector_type(8))) short bfrag8;   // 8 bf16 (4 VGPRs)
typedef __attribute__((ext_vector_type(4))) float f32x4;    // 4 fp32 acc

// ---------------- bf16 helpers ----------------
__device__ __forceinline__ unsigned f2bf_rne(float x) {
    unsigned u = __float_as_uint(x);
    return (u + 0x7fffu + ((u >> 16) & 1u)) >> 16;
}
__device__ __forceinline__ float bf2f(unsigned u) {
    return __uint_as_float(u << 16);
}

// ---------------- CSR build ----------------
__global__ void degree_kernel(const int* __restrict__ dst, int* __restrict__ cnt, int E) {
    int e = blockIdx.x * 256 + threadIdx.x;
    if (e < E) atomicAdd(&cnt[dst[e]], 1);
}

__global__ __launch_bounds__(1024) void scan1_kernel(const int* __restrict__ cnt,
                                                     int* __restrict__ partial,
                                                     int* __restrict__ bsum, int N) {
    __shared__ int sdata[SCANB];
    int i = blockIdx.x * SCANB + (int)threadIdx.x;
    int v = (i < N) ? cnt[i] : 0;
    sdata[threadIdx.x] = v;
    __syncthreads();
    for (int off = 1; off < SCANB; off <<= 1) {
        int t = (threadIdx.x >= (unsigned)off) ? sdata[threadIdx.x - off] : 0;
        __syncthreads();
        sdata[threadIdx.x] += t;
        __syncthreads();
    }
    if (i < N) partial[i] = sdata[threadIdx.x];
    if (threadIdx.x == SCANB - 1) bsum[blockIdx.x] = sdata[SCANB - 1];
}

__global__ void scan2_kernel(const int* __restrict__ bsum, int* __restrict__ boff, int nb) {
    int lane = threadIdx.x;   // 64 threads
    int v = (lane < nb) ? bsum[lane] : 0;
#pragma unroll
    for (int off = 1; off < 64; off <<= 1) {
        int o = __shfl_up(v, off, 64);
        if (lane >= off) v += o;
    }
    int excl = __shfl_up(v, 1, 64);
    if (lane == 0) excl = 0;
    if (lane < nb) boff[lane] = excl;
}

__global__ __launch_bounds__(1024) void scan3_kernel(const int* __restrict__ partial,
                                                     const int* __restrict__ boff,
                                                     int* __restrict__ rowptr,
                                                     int* __restrict__ cursor, int N) {
    int i = blockIdx.x * SCANB + (int)threadIdx.x;
    if (i < N) {
        int inc = partial[i] + boff[blockIdx.x];
        rowptr[i + 1] = inc;
        if (i + 1 < N) cursor[i + 1] = inc;
    }
    if (i == 0) { rowptr[0] = 0; cursor[0] = 0; }
}

__global__ void scatter_kernel(const int* __restrict__ src, const int* __restrict__ dst,
                               int* __restrict__ cursor, int* __restrict__ srcs, int E) {
    int e = blockIdx.x * 256 + threadIdx.x;
    if (e < E) {
        int pos = atomicAdd(&cursor[dst[e]], 1);
        srcs[pos] = src[e];
    }
}

// ---------------- W split+transpose: B[256][256] fp32 -> Bth/Btl[n][k] bf16 ----------------
__global__ __launch_bounds__(256) void bconv_kernel(const float* __restrict__ B,
                                                    ushort* __restrict__ Bth,
                                                    ushort* __restrict__ Btl) {
    __shared__ ushort th[16][264], tl[16][264];
    int k0 = blockIdx.x * 16;
    int n = threadIdx.x;
#pragma unroll
    for (int k = 0; k < 16; ++k) {
        float v = B[(size_t)(k0 + k) * 256 + n];
        unsigned hb = f2bf_rne(v);
        th[k][n] = (ushort)hb;
        tl[k][n] = (ushort)(__float_as_uint(v - bf2f(hb)) >> 16);
    }
    __syncthreads();
    ushort oh[16], ol[16];
#pragma unroll
    for (int k = 0; k < 16; ++k) { oh[k] = th[k][n]; ol[k] = tl[k][n]; }
#pragma unroll
    for (int q = 0; q < 4; ++q) {
        *reinterpret_cast<ushort4*>(Bth + (size_t)n * 256 + k0 + q * 4) =
            make_ushort4(oh[q*4+0], oh[q*4+1], oh[q*4+2], oh[q*4+3]);
        *reinterpret_cast<ushort4*>(Btl + (size_t)n * 256 + k0 + q * 4) =
            make_ushort4(ol[q*4+0], ol[q*4+1], ol[q*4+2], ol[q*4+3]);
    }
}

// ---------------- GEMM: Cb[M,256](bf16) = Ah @ (Bh+Bl), 2-pass split-bf16 MFMA ----------------
// A rounded to bf16 (error ~2^-9 rel, below the bf16 OUTPUT rounding of Cb).
// SPLITA=1: A fp32, rounded inline during staging (layer 1).
// SPLITA=0: A pre-rounded bf16 (layer 2: agg1's hi output).
template <int SPLITA>
__global__ __launch_bounds__(256) void gemm_mfma_kernel(const float* __restrict__ Af,
                                                        const ushort* __restrict__ Ahg,
                                                        const ushort* __restrict__ Bth,
                                                        const ushort* __restrict__ Btl,
                                                        ushort* __restrict__ Cb, int M) {
    __shared__ ushort Ah[128][40];                // [m][k], 80B row stride (bank-spread)
    __shared__ ushort Bh[128][40], Bl[128][40];   // [n][k]
    const int t = threadIdx.x;
    const int lane = t & 63, wave = t >> 6;
    const int wr = wave >> 1, wc = wave & 1;
    const int row0 = blockIdx.x * 128;
    const int col0 = blockIdx.y * 128;

    f32x4 acc[4][4];
#pragma unroll
    for (int i = 0; i < 4; ++i)
#pragma unroll
        for (int j = 0; j < 4; ++j) { acc[i][j].x = 0.f; acc[i][j].y = 0.f; acc[i][j].z = 0.f; acc[i][j].w = 0.f; }

    const int srow = t >> 1;            // 0..127
    const int skoff = (t & 1) * 16;     // 0 or 16
    int arow = row0 + srow; if (arow >= M) arow = M - 1;   // clamp; stores guarded
    const size_t abase = (size_t)arow * 256 + skoff;
    const size_t bbase = (size_t)(col0 + srow) * 256 + skoff;

    float4 af0, af1, af2, af3;          // SPLITA: 16 fp32 of A
    uint4 r0, r1;                       // !SPLITA: Ah 16B x2
    uint4 r4, r5, r6, r7;               // B hi/lo

#define LOADK(kk)                                                              \
    do {                                                                       \
        if constexpr (SPLITA) {                                                \
            const float4* pa = reinterpret_cast<const float4*>(Af + abase + (kk)); \
            af0 = pa[0]; af1 = pa[1]; af2 = pa[2]; af3 = pa[3];                \
        } else {                                                               \
            r0 = *reinterpret_cast<const uint4*>(Ahg + abase + (kk));          \
            r1 = *reinterpret_cast<const uint4*>(Ahg + abase + (kk) + 8);      \
        }                                                                      \
        r4 = *reinterpret_cast<const uint4*>(Bth + bbase + (kk));              \
        r5 = *reinterpret_cast<const uint4*>(Bth + bbase + (kk) + 8);          \
        r6 = *reinterpret_cast<const uint4*>(Btl + bbase + (kk));              \
        r7 = *reinterpret_cast<const uint4*>(Btl + bbase + (kk) + 8);          \
    } while (0)

    LOADK(0);
#pragma unroll
    for (int kk = 0; kk < 256; kk += 32) {
        if (kk) __syncthreads();
        if constexpr (SPLITA) {
            float v[16];
            v[0]=af0.x; v[1]=af0.y; v[2]=af0.z; v[3]=af0.w;
            v[4]=af1.x; v[5]=af1.y; v[6]=af1.z; v[7]=af1.w;
            v[8]=af2.x; v[9]=af2.y; v[10]=af2.z; v[11]=af2.w;
            v[12]=af3.x; v[13]=af3.y; v[14]=af3.z; v[15]=af3.w;
            ushort hh[16];
#pragma unroll
            for (int q = 0; q < 16; ++q) hh[q] = (ushort)f2bf_rne(v[q]);
#pragma unroll
            for (int q = 0; q < 4; ++q) {
                *reinterpret_cast<ushort4*>(&Ah[srow][skoff + q * 4]) =
                    make_ushort4(hh[q*4+0], hh[q*4+1], hh[q*4+2], hh[q*4+3]);
            }
        } else {
            *reinterpret_cast<uint4*>(&Ah[srow][skoff])     = r0;
            *reinterpret_cast<uint4*>(&Ah[srow][skoff + 8]) = r1;
        }
        *reinterpret_cast<uint4*>(&Bh[srow][skoff])     = r4;
        *reinterpret_cast<uint4*>(&Bh[srow][skoff + 8]) = r5;
        *reinterpret_cast<uint4*>(&Bl[srow][skoff])     = r6;
        *reinterpret_cast<uint4*>(&Bl[srow][skoff + 8]) = r7;
        __syncthreads();
        if (kk + 32 < 256) LOADK(kk + 32);   // latency hides under MFMA below

        const int kg = (lane >> 4) * 8;
        const int rsel = lane & 15;
        bfrag8 afh[4], bfh[4], bfl[4];
#pragma unroll
        for (int i = 0; i < 4; ++i)
            afh[i] = *reinterpret_cast<const bfrag8*>(&Ah[wr * 64 + i * 16 + rsel][kg]);
#pragma unroll
        for (int j = 0; j < 4; ++j) {
            bfh[j] = *reinterpret_cast<const bfrag8*>(&Bh[wc * 64 + j * 16 + rsel][kg]);
            bfl[j] = *reinterpret_cast<const bfrag8*>(&Bl[wc * 64 + j * 16 + rsel][kg]);
        }
#pragma unroll
        for (int i = 0; i < 4; ++i)
#pragma unroll
            for (int j = 0; j < 4; ++j) {
                acc[i][j] = __builtin_amdgcn_mfma_f32_16x16x32_bf16(afh[i], bfh[j], acc[i][j], 0, 0, 0);
                acc[i][j] = __builtin_amdgcn_mfma_f32_16x16x32_bf16(afh[i], bfl[j], acc[i][j], 0, 0, 0);
            }
    }
#undef LOADK
    const int ccol = lane & 15;
    const int crow = (lane >> 4) * 4;
#pragma unroll
    for (int i = 0; i < 4; ++i) {
#pragma unroll
        for (int r = 0; r < 4; ++r) {
            int row = row0 + wr * 64 + i * 16 + crow + r;
            if (row >= M) continue;
#pragma unroll
            for (int j = 0; j < 4; ++j) {
                int col = col0 + wc * 64 + j * 16 + ccol;
                float val = (r == 0) ? acc[i][j].x : (r == 1) ? acc[i][j].y : (r == 2) ? acc[i][j].z : acc[i][j].w;
                Cb[(size_t)row * 256 + col] = (ushort)f2bf_rne(val);
            }
        }
    }
}

// ---------------- el/er: per-node head dots (bf16 feat) ----------------
__global__ void eler_kernel(const ushort* __restrict__ featb, const float* __restrict__ al,
                            const float* __restrict__ ar, float* __restrict__ el,
                            float* __restrict__ er, int N) {
    int node = blockIdx.x * 4 + (threadIdx.x >> 6);
    if (node >= N) return;
    int lane = threadIdx.x & 63;
    ushort4 fu = *reinterpret_cast<const ushort4*>(featb + (size_t)node * FDIM + lane * 4);
    float f0 = bf2f(fu.x), f1 = bf2f(fu.y), f2 = bf2f(fu.z), f3 = bf2f(fu.w);
    float4 a = *reinterpret_cast<const float4*>(al + lane * 4);
    float4 b = *reinterpret_cast<const float4*>(ar + lane * 4);
    float pl = f0 * a.x + f1 * a.y + f2 * a.z + f3 * a.w;
    float pr = f0 * b.x + f1 * b.y + f2 * b.z + f3 * b.w;
#pragma unroll
    for (int m = 1; m < 16; m <<= 1) {
        pl += __shfl_xor(pl, m, 64);
        pr += __shfl_xor(pr, m, 64);
    }
    if ((lane & 15) == 0) {
        int h = lane >> 4;
        el[node * NHEAD + h] = pl;
        er[node * NHEAD + h] = pr;
    }
}

// ---------------- fused softmax + aggregation, one wave per node ----------------
// Phase A: stats with (16 edges x 4 heads) on 64 lanes — each exp computed once.
// Phase B: per chunk, each lane computes ONE weight; shuffle-broadcast into the
//          gather loop (no w materialization, no redundant exp), 4 accumulators.
__global__ __launch_bounds__(256) void agg_kernel(
        const ushort* __restrict__ featb, const float* __restrict__ el,
        const float* __restrict__ er, const int* __restrict__ rowptr,
        const int* __restrict__ srcs,
        const ushort* __restrict__ resid_h, const ushort* __restrict__ resid_l,
        float* __restrict__ outf, ushort* __restrict__ outh, ushort* __restrict__ outl,
        int N) {
    int node = blockIdx.x * 4 + (threadIdx.x >> 6);
    if (node >= N) return;
    int lane = threadIdx.x & 63;
    int h4 = lane & 3;        // head for stats/weights
    int eo = lane >> 2;       // edge slot within 16-chunk
    int head = lane >> 4;     // head for gather (feature layout)
    float erh = er[(size_t)node * NHEAD + h4];
    int beg = rowptr[node], end = rowptr[node + 1];

    // ---- phase A: max & denom per head ----
    float m = -1e30f, ls = 0.f;
    for (int base = beg; base < end; base += 16) {
        int p = base + eo;
        float x = -1e30f;
        if (p < end) {
            int s = srcs[p];
            float t = el[(size_t)s * NHEAD + h4] + erh;
            x = t > 0.f ? t : 0.2f * t;
        }
        float cm = x;   // reduce over the 16 lanes sharing head h4
        cm = fmaxf(cm, __shfl_xor(cm, 4, 64));
        cm = fmaxf(cm, __shfl_xor(cm, 8, 64));
        cm = fmaxf(cm, __shfl_xor(cm, 16, 64));
        cm = fmaxf(cm, __shfl_xor(cm, 32, 64));
        float mn = fmaxf(m, cm);
        ls = ls * __expf(m - mn) + ((p < end) ? __expf(x - mn) : 0.f);
        m = mn;
    }
    ls += __shfl_xor(ls, 4, 64);
    ls += __shfl_xor(ls, 8, 64);
    ls += __shfl_xor(ls, 16, 64);
    ls += __shfl_xor(ls, 32, 64);
    float dinv = ls > 0.f ? 1.0f / ls : 0.f;

    // ---- phase B: weighted gather with shuffle-broadcast weights ----
    f32x4 a0 = {0.f, 0.f, 0.f, 0.f}, a1 = a0, a2 = a0, a3 = a0;
    for (int base = beg; base < end; base += 16) {
        int p = base + eo;
        int smine = 0;
        float wmine = 0.f;
        if (p < end) {
            smine = srcs[p];
            float t = el[(size_t)smine * NHEAD + h4] + erh;
            t = t > 0.f ? t : 0.2f * t;
            wmine = __expf(t - m) * dinv;
        }
        int jmax = end - base; if (jmax > 16) jmax = 16;   // wave-uniform bound
        int j = 0;
        for (; j + 3 < jmax; j += 4) {
            int sl0 = 4 * j + head;
            int s0 = __shfl(smine, sl0, 64);
            int s1 = __shfl(smine, sl0 + 4, 64);
            int s2 = __shfl(smine, sl0 + 8, 64);
            int s3 = __shfl(smine, sl0 + 12, 64);
            float w0 = __shfl(wmine, sl0, 64);
            float w1 = __shfl(wmine, sl0 + 4, 64);
            float w2 = __shfl(wmine, sl0 + 8, 64);
            float w3 = __shfl(wmine, sl0 + 12, 64);
            ushort4 f0 = *reinterpret_cast<const ushort4*>(featb + (size_t)s0 * FDIM + lane * 4);
            ushort4 f1 = *reinterpret_cast<const ushort4*>(featb + (size_t)s1 * FDIM + lane * 4);
            ushort4 f2 = *reinterpret_cast<const ushort4*>(featb + (size_t)s2 * FDIM + lane * 4);
            ushort4 f3 = *reinterpret_cast<const ushort4*>(featb + (size_t)s3 * FDIM + lane * 4);
            a0.x = fmaf(w0, bf2f(f0.x), a0.x); a0.y = fmaf(w0, bf2f(f0.y), a0.y);
            a0.z = fmaf(w0, bf2f(f0.z), a0.z); a0.w = fmaf(w0, bf2f(f0.w), a0.w);
            a1.x = fmaf(w1, bf2f(f1.x), a1.x); a1.y = fmaf(w1, bf2f(f1.y), a1.y);
            a1.z = fmaf(w1, bf2f(f1.z), a1.z); a1.w = fmaf(w1, bf2f(f1.w), a1.w);
            a2.x = fmaf(w2, bf2f(f2.x), a2.x); a2.y = fmaf(w2, bf2f(f2.y), a2.y);
            a2.z = fmaf(w2, bf2f(f2.z), a2.z); a2.w = fmaf(w2, bf2f(f2.w), a2.w);
            a3.x = fmaf(w3, bf2f(f3.x), a3.x); a3.y = fmaf(w3, bf2f(f3.y), a3.y);
            a3.z = fmaf(w3, bf2f(f3.z), a3.z); a3.w = fmaf(w3, bf2f(f3.w), a3.w);
        }
        for (; j < jmax; ++j) {
            int sl = 4 * j + head;
            int s0 = __shfl(smine, sl, 64);
            float w0 = __shfl(wmine, sl, 64);
            ushort4 f0 = *reinterpret_cast<const ushort4*>(featb + (size_t)s0 * FDIM + lane * 4);
            a0.x = fmaf(w0, bf2f(f0.x), a0.x); a0.y = fmaf(w0, bf2f(f0.y), a0.y);
            a0.z = fmaf(w0, bf2f(f0.z), a0.z); a0.w = fmaf(w0, bf2f(f0.w), a0.w);
        }
    }
    float4 acc = make_float4(a0.x + a1.x + a2.x + a3.x, a0.y + a1.y + a2.y + a3.y,
                             a0.z + a1.z + a2.z + a3.z, a0.w + a1.w + a2.w + a3.w);

    if (resid_h) {
        ushort4 rh = *reinterpret_cast<const ushort4*>(resid_h + (size_t)node * FDIM + lane * 4);
        ushort4 rl = *reinterpret_cast<const ushort4*>(resid_l + (size_t)node * FDIM + lane * 4);
        acc.x += bf2f(rh.x) + bf2f(rl.x);
        acc.y += bf2f(rh.y) + bf2f(rl.y);
        acc.z += bf2f(rh.z) + bf2f(rl.z);
        acc.w += bf2f(rh.w) + bf2f(rl.w);
    }
    acc.x = acc.x > 0.f ? acc.x : expm1f(acc.x);
    acc.y = acc.y > 0.f ? acc.y : expm1f(acc.y);
    acc.z = acc.z > 0.f ? acc.z : expm1f(acc.z);
    acc.w = acc.w > 0.f ? acc.w : expm1f(acc.w);

    if (outf) {
        *reinterpret_cast<float4*>(outf + (size_t)node * FDIM + lane * 4) = acc;
    } else {
        unsigned h0 = f2bf_rne(acc.x), h1 = f2bf_rne(acc.y), h2 = f2bf_rne(acc.z), h3 = f2bf_rne(acc.w);
        *reinterpret_cast<ushort4*>(outh + (size_t)node * FDIM + lane * 4) =
            make_ushort4((ushort)h0, (ushort)h1, (ushort)h2, (ushort)h3);
        *reinterpret_cast<ushort4*>(outl + (size_t)node * FDIM + lane * 4) = make_ushort4(
            (ushort)(__float_as_uint(acc.x - bf2f(h0)) >> 16),
            (ushort)(__float_as_uint(acc.y - bf2f(h1)) >> 16),
            (ushort)(__float_as_uint(acc.z - bf2f(h2)) >> 16),
            (ushort)(__float_as_uint(acc.w - bf2f(h3)) >> 16));
    }
}

// ---------------- launch ----------------
extern "C" void kernel_launch(void* const* d_in, const int* in_sizes, int n_in,
                              void* d_out, int out_size, void* d_ws, size_t ws_size,
                              hipStream_t stream) {
    const float* features = (const float*)d_in[0];
    const int*   src      = (const int*)d_in[1];
    const int*   dst      = (const int*)d_in[2];
    const float* W1       = (const float*)d_in[3];
    const float* al1      = (const float*)d_in[4];
    const float* ar1      = (const float*)d_in[5];
    const float* W2       = (const float*)d_in[6];
    const float* al2      = (const float*)d_in[7];
    const float* ar2      = (const float*)d_in[8];
    float* out = (float*)d_out;

    const int N = N_NODES, E = N_EDGES;

    char* ws = (char*)d_ws;
    size_t off = 0;
    auto alloc = [&](size_t bytes) -> void* {
        void* p = ws + off;
        off = (off + bytes + 255) & ~(size_t)255;
        return p;
    };
    ushort* featb  = (ushort*)alloc((size_t)N * FDIM * 2);
    ushort* Afh    = (ushort*)alloc((size_t)N * FDIM * 2);   // layer-1 output hi (agg1 out)
    ushort* Afl    = (ushort*)alloc((size_t)N * FDIM * 2);   // layer-1 output lo (residual only)
    float*  el     = (float*)alloc((size_t)N * NHEAD * 4);
    float*  er     = (float*)alloc((size_t)N * NHEAD * 4);
    int*    rowptr = (int*)alloc((size_t)(N + 1) * 4);
    int*    cnt    = (int*)alloc((size_t)N * 4);
    int*    cursor = (int*)alloc((size_t)N * 4);
    int*    partial= (int*)alloc((size_t)N * 4);
    int*    bsum   = (int*)alloc((size_t)NSCAN * 4);
    int*    boff   = (int*)alloc((size_t)NSCAN * 4);
    int*    srcs   = (int*)alloc((size_t)E * 4);
    ushort* Bth    = (ushort*)alloc((size_t)256 * 256 * 2);
    ushort* Btl    = (ushort*)alloc((size_t)256 * 256 * 2);

    const int egrid = (E + 255) / 256;
    const int ngrid4 = (N + 3) / 4;

    // ---- CSR build (by dst) ----
    hipMemsetAsync(cnt, 0, (size_t)N * 4, stream);
    degree_kernel<<<egrid, 256, 0, stream>>>(dst, cnt, E);
    scan1_kernel<<<NSCAN, SCANB, 0, stream>>>(cnt, partial, bsum, N);
    scan2_kernel<<<1, 64, 0, stream>>>(bsum, boff, NSCAN);
    scan3_kernel<<<NSCAN, SCANB, 0, stream>>>(partial, boff, rowptr, cursor, N);
    scatter_kernel<<<egrid, 256, 0, stream>>>(src, dst, cursor, srcs, E);

    dim3 ggrid((N + 127) / 128, 2);

    // ---- layer 1 (A = fp32 features, rounded inline in GEMM) ----
    bconv_kernel<<<16, 256, 0, stream>>>(W1, Bth, Btl);
    gemm_mfma_kernel<1><<<ggrid, 256, 0, stream>>>(features, nullptr, Bth, Btl, featb, N);
    eler_kernel<<<ngrid4, 256, 0, stream>>>(featb, al1, ar1, el, er, N);
    agg_kernel<<<ngrid4, 256, 0, stream>>>(featb, el, er, rowptr, srcs,
                                           nullptr, nullptr, nullptr, Afh, Afl, N);

    // ---- layer 2 (A = layer-1 output hi; residual = hi+lo) ----
    bconv_kernel<<<16, 256, 0, stream>>>(W2, Bth, Btl);
    gemm_mfma_kernel<0><<<ggrid, 256, 0, stream>>>(nullptr, Afh, Bth, Btl, featb, N);
    eler_kernel<<<ngrid4, 256, 0, stream>>>(featb, al2, ar2, el, er, N);
    agg_kernel<<<ngrid4, 256, 0, stream>>>(featb, el, er, rowptr, srcs,
                                           Afh, Afl, out, nullptr, nullptr, N);
}

// Round 9
// 304.427 us; speedup vs baseline: 1.1092x; 1.0565x over previous
//
#include <hip/hip_runtime.h>
#include <hip/hip_bf16.h>

#define N_NODES 50000
#define N_EDGES 800000
#define NHEAD 4
#define DHEAD 64
#define FDIM 256   // NHEAD*DHEAD == in_feats == out_feats
#define SCANB 1024
#define NSCAN ((N_NODES + SCANB - 1) / SCANB)   // 49

typedef __attribute__((ext_vector_type(8))) short bfrag8;   // 8 bf16 (4 VGPRs)
typedef __attribute__((ext_vector_type(4))) float f32x4;    // 4 fp32 acc

// ---------------- bf16 helpers ----------------
__device__ __forceinline__ unsigned f2bf_rne(float x) {
    unsigned u = __float_as_uint(x);
    return (u + 0x7fffu + ((u >> 16) & 1u)) >> 16;
}
__device__ __forceinline__ float bf2f(unsigned u) {
    return __uint_as_float(u << 16);
}

// ---------------- CSR build ----------------
__global__ void degree_kernel(const int* __restrict__ dst, int* __restrict__ cnt, int E) {
    int e = blockIdx.x * 256 + threadIdx.x;
    if (e < E) atomicAdd(&cnt[dst[e]], 1);
}

__global__ __launch_bounds__(1024) void scan1_kernel(const int* __restrict__ cnt,
                                                     int* __restrict__ partial,
                                                     int* __restrict__ bsum, int N) {
    __shared__ int sdata[SCANB];
    int i = blockIdx.x * SCANB + (int)threadIdx.x;
    int v = (i < N) ? cnt[i] : 0;
    sdata[threadIdx.x] = v;
    __syncthreads();
    for (int off = 1; off < SCANB; off <<= 1) {
        int t = (threadIdx.x >= (unsigned)off) ? sdata[threadIdx.x - off] : 0;
        __syncthreads();
        sdata[threadIdx.x] += t;
        __syncthreads();
    }
    if (i < N) partial[i] = sdata[threadIdx.x];
    if (threadIdx.x == SCANB - 1) bsum[blockIdx.x] = sdata[SCANB - 1];
}

__global__ void scan2_kernel(const int* __restrict__ bsum, int* __restrict__ boff, int nb) {
    int lane = threadIdx.x;   // 64 threads
    int v = (lane < nb) ? bsum[lane] : 0;
#pragma unroll
    for (int off = 1; off < 64; off <<= 1) {
        int o = __shfl_up(v, off, 64);
        if (lane >= off) v += o;
    }
    int excl = __shfl_up(v, 1, 64);
    if (lane == 0) excl = 0;
    if (lane < nb) boff[lane] = excl;
}

__global__ __launch_bounds__(1024) void scan3_kernel(const int* __restrict__ partial,
                                                     const int* __restrict__ boff,
                                                     int* __restrict__ rowptr,
                                                     int* __restrict__ cursor, int N) {
    int i = blockIdx.x * SCANB + (int)threadIdx.x;
    if (i < N) {
        int inc = partial[i] + boff[blockIdx.x];
        rowptr[i + 1] = inc;
        if (i + 1 < N) cursor[i + 1] = inc;
    }
    if (i == 0) { rowptr[0] = 0; cursor[0] = 0; }
}

__global__ void scatter_kernel(const int* __restrict__ src, const int* __restrict__ dst,
                               int* __restrict__ cursor, int* __restrict__ srcs, int E) {
    int e = blockIdx.x * 256 + threadIdx.x;
    if (e < E) {
        int pos = atomicAdd(&cursor[dst[e]], 1);
        srcs[pos] = src[e];
    }
}

// ---------------- W round+transpose (both layers, one dispatch) ----------------
// Bt[n][k] = bf16(B[k][n]); blockIdx.y selects layer.
__global__ __launch_bounds__(256) void bconv_kernel(const float* __restrict__ B1,
                                                    const float* __restrict__ B2,
                                                    ushort* __restrict__ Bt1,
                                                    ushort* __restrict__ Bt2) {
    const float* B = blockIdx.y ? B2 : B1;
    ushort* Bt = blockIdx.y ? Bt2 : Bt1;
    __shared__ ushort th[16][264];
    int k0 = blockIdx.x * 16;
    int n = threadIdx.x;
#pragma unroll
    for (int k = 0; k < 16; ++k)
        th[k][n] = (ushort)f2bf_rne(B[(size_t)(k0 + k) * 256 + n]);
    __syncthreads();
    ushort oh[16];
#pragma unroll
    for (int k = 0; k < 16; ++k) oh[k] = th[k][n];
#pragma unroll
    for (int q = 0; q < 4; ++q)
        *reinterpret_cast<ushort4*>(Bt1 == Bt ? Bt1 + (size_t)n * 256 + k0 + q * 4
                                              : Bt2 + (size_t)n * 256 + k0 + q * 4) =
            make_ushort4(oh[q*4+0], oh[q*4+1], oh[q*4+2], oh[q*4+3]);
}

// ---------------- GEMM + fused el/er epilogue ----------------
// Cb[M,256](bf16) = Ah @ Bt, 1-pass bf16 MFMA.
// Epilogue: wave (wr,wc)'s C-fragment covers head (col0>>6)+wc entirely, so
// el/er per-row dots reduce with 4 fma + shfl_xor(1,2,4,8); block-cols cover
// disjoint heads -> plain stores, no atomics, no pre-zeroing.
// SPLITA=1: A fp32, rounded inline during staging (layer 1).
// SPLITA=0: A pre-rounded bf16 (layer 2: agg1's hi output).
template <int SPLITA>
__global__ __launch_bounds__(256) void gemm_mfma_kernel(const float* __restrict__ Af,
                                                        const ushort* __restrict__ Ahg,
                                                        const ushort* __restrict__ Bt,
                                                        ushort* __restrict__ Cb,
                                                        const float* __restrict__ al,
                                                        const float* __restrict__ ar,
                                                        float* __restrict__ el,
                                                        float* __restrict__ er, int M) {
    __shared__ ushort Ah[128][40];   // [m][k], 80B row stride (bank-spread)
    __shared__ ushort Bh[128][40];   // [n][k]
    const int t = threadIdx.x;
    const int lane = t & 63, wave = t >> 6;
    const int wr = wave >> 1, wc = wave & 1;
    const int row0 = blockIdx.x * 128;
    const int col0 = blockIdx.y * 128;

    f32x4 acc[4][4];
#pragma unroll
    for (int i = 0; i < 4; ++i)
#pragma unroll
        for (int j = 0; j < 4; ++j) { acc[i][j].x = 0.f; acc[i][j].y = 0.f; acc[i][j].z = 0.f; acc[i][j].w = 0.f; }

    const int srow = t >> 1;            // 0..127
    const int skoff = (t & 1) * 16;     // 0 or 16
    int arow = row0 + srow; if (arow >= M) arow = M - 1;   // clamp; stores guarded
    const size_t abase = (size_t)arow * 256 + skoff;
    const size_t bbase = (size_t)(col0 + srow) * 256 + skoff;

    float4 af0, af1, af2, af3;          // SPLITA: 16 fp32 of A
    uint4 r0, r1;                       // !SPLITA: Ah 16B x2
    uint4 r4, r5;                       // B

#define LOADK(kk)                                                              \
    do {                                                                       \
        if constexpr (SPLITA) {                                                \
            const float4* pa = reinterpret_cast<const float4*>(Af + abase + (kk)); \
            af0 = pa[0]; af1 = pa[1]; af2 = pa[2]; af3 = pa[3];                \
        } else {                                                               \
            r0 = *reinterpret_cast<const uint4*>(Ahg + abase + (kk));          \
            r1 = *reinterpret_cast<const uint4*>(Ahg + abase + (kk) + 8);      \
        }                                                                      \
        r4 = *reinterpret_cast<const uint4*>(Bt + bbase + (kk));               \
        r5 = *reinterpret_cast<const uint4*>(Bt + bbase + (kk) + 8);           \
    } while (0)

    LOADK(0);
#pragma unroll
    for (int kk = 0; kk < 256; kk += 32) {
        if (kk) __syncthreads();
        if constexpr (SPLITA) {
            float v[16];
            v[0]=af0.x; v[1]=af0.y; v[2]=af0.z; v[3]=af0.w;
            v[4]=af1.x; v[5]=af1.y; v[6]=af1.z; v[7]=af1.w;
            v[8]=af2.x; v[9]=af2.y; v[10]=af2.z; v[11]=af2.w;
            v[12]=af3.x; v[13]=af3.y; v[14]=af3.z; v[15]=af3.w;
            ushort hh[16];
#pragma unroll
            for (int q = 0; q < 16; ++q) hh[q] = (ushort)f2bf_rne(v[q]);
#pragma unroll
            for (int q = 0; q < 4; ++q)
                *reinterpret_cast<ushort4*>(&Ah[srow][skoff + q * 4]) =
                    make_ushort4(hh[q*4+0], hh[q*4+1], hh[q*4+2], hh[q*4+3]);
        } else {
            *reinterpret_cast<uint4*>(&Ah[srow][skoff])     = r0;
            *reinterpret_cast<uint4*>(&Ah[srow][skoff + 8]) = r1;
        }
        *reinterpret_cast<uint4*>(&Bh[srow][skoff])     = r4;
        *reinterpret_cast<uint4*>(&Bh[srow][skoff + 8]) = r5;
        __syncthreads();
        if (kk + 32 < 256) LOADK(kk + 32);   // latency hides under MFMA below

        const int kg = (lane >> 4) * 8;
        const int rsel = lane & 15;
        bfrag8 afh[4], bfh[4];
#pragma unroll
        for (int i = 0; i < 4; ++i)
            afh[i] = *reinterpret_cast<const bfrag8*>(&Ah[wr * 64 + i * 16 + rsel][kg]);
#pragma unroll
        for (int j = 0; j < 4; ++j)
            bfh[j] = *reinterpret_cast<const bfrag8*>(&Bh[wc * 64 + j * 16 + rsel][kg]);
#pragma unroll
        for (int i = 0; i < 4; ++i)
#pragma unroll
            for (int j = 0; j < 4; ++j)
                acc[i][j] = __builtin_amdgcn_mfma_f32_16x16x32_bf16(afh[i], bfh[j], acc[i][j], 0, 0, 0);
    }
#undef LOADK

    // ---- epilogue: C store + fused el/er ----
    const int ccol = lane & 15;
    const int crow = (lane >> 4) * 4;
    const int head = (col0 >> 6) + wc;   // this wave's head (disjoint across by/wc)
    float alv[4], arv[4];
#pragma unroll
    for (int j = 0; j < 4; ++j) {
        alv[j] = al[head * 64 + j * 16 + ccol];
        arv[j] = ar[head * 64 + j * 16 + ccol];
    }
#pragma unroll
    for (int i = 0; i < 4; ++i) {
#pragma unroll
        for (int r = 0; r < 4; ++r) {
            int row = row0 + wr * 64 + i * 16 + crow + r;
            float vj[4];
#pragma unroll
            for (int j = 0; j < 4; ++j)
                vj[j] = (r == 0) ? acc[i][j].x : (r == 1) ? acc[i][j].y : (r == 2) ? acc[i][j].z : acc[i][j].w;
            // el/er partial over this lane's 4 cols, reduce across 16 ccol-lanes
            float pl = 0.f, pr = 0.f;
#pragma unroll
            for (int j = 0; j < 4; ++j) {
                pl = fmaf(vj[j], alv[j], pl);
                pr = fmaf(vj[j], arv[j], pr);
            }
#pragma unroll
            for (int msk = 1; msk < 16; msk <<= 1) {
                pl += __shfl_xor(pl, msk, 64);
                pr += __shfl_xor(pr, msk, 64);
            }
            if (row < M) {
                if (ccol == 0) {
                    el[(size_t)row * NHEAD + head] = pl;
                    er[(size_t)row * NHEAD + head] = pr;
                }
#pragma unroll
                for (int j = 0; j < 4; ++j) {
                    int col = col0 + wc * 64 + j * 16 + ccol;
                    Cb[(size_t)row * 256 + col] = (ushort)f2bf_rne(vj[j]);
                }
            }
        }
    }
}

// ---------------- fused softmax + aggregation, one wave per node ----------------
// Phase A: stats with (16 edges x 4 heads) on 64 lanes — each exp computed once.
// Phase B: per chunk, each lane computes ONE weight; shuffle-broadcast into the
//          gather loop (no w materialization, no redundant exp), 4 accumulators.
__global__ __launch_bounds__(256) void agg_kernel(
        const ushort* __restrict__ featb, const float* __restrict__ el,
        const float* __restrict__ er, const int* __restrict__ rowptr,
        const int* __restrict__ srcs,
        const ushort* __restrict__ resid_h, const ushort* __restrict__ resid_l,
        float* __restrict__ outf, ushort* __restrict__ outh, ushort* __restrict__ outl,
        int N) {
    int node = blockIdx.x * 4 + (threadIdx.x >> 6);
    if (node >= N) return;
    int lane = threadIdx.x & 63;
    int h4 = lane & 3;        // head for stats/weights
    int eo = lane >> 2;       // edge slot within 16-chunk
    int head = lane >> 4;     // head for gather (feature layout)
    float erh = er[(size_t)node * NHEAD + h4];
    int beg = rowptr[node], end = rowptr[node + 1];

    // ---- phase A: max & denom per head ----
    float m = -1e30f, ls = 0.f;
    for (int base = beg; base < end; base += 16) {
        int p = base + eo;
        float x = -1e30f;
        if (p < end) {
            int s = srcs[p];
            float t = el[(size_t)s * NHEAD + h4] + erh;
            x = t > 0.f ? t : 0.2f * t;
        }
        float cm = x;   // reduce over the 16 lanes sharing head h4
        cm = fmaxf(cm, __shfl_xor(cm, 4, 64));
        cm = fmaxf(cm, __shfl_xor(cm, 8, 64));
        cm = fmaxf(cm, __shfl_xor(cm, 16, 64));
        cm = fmaxf(cm, __shfl_xor(cm, 32, 64));
        float mn = fmaxf(m, cm);
        ls = ls * __expf(m - mn) + ((p < end) ? __expf(x - mn) : 0.f);
        m = mn;
    }
    ls += __shfl_xor(ls, 4, 64);
    ls += __shfl_xor(ls, 8, 64);
    ls += __shfl_xor(ls, 16, 64);
    ls += __shfl_xor(ls, 32, 64);
    float dinv = ls > 0.f ? 1.0f / ls : 0.f;

    // ---- phase B: weighted gather with shuffle-broadcast weights ----
    f32x4 a0 = {0.f, 0.f, 0.f, 0.f}, a1 = a0, a2 = a0, a3 = a0;
    for (int base = beg; base < end; base += 16) {
        int p = base + eo;
        int smine = 0;
        float wmine = 0.f;
        if (p < end) {
            smine = srcs[p];
            float t = el[(size_t)smine * NHEAD + h4] + erh;
            t = t > 0.f ? t : 0.2f * t;
            wmine = __expf(t - m) * dinv;
        }
        int jmax = end - base; if (jmax > 16) jmax = 16;   // wave-uniform bound
        int j = 0;
        for (; j + 3 < jmax; j += 4) {
            int sl0 = 4 * j + head;
            int s0 = __shfl(smine, sl0, 64);
            int s1 = __shfl(smine, sl0 + 4, 64);
            int s2 = __shfl(smine, sl0 + 8, 64);
            int s3 = __shfl(smine, sl0 + 12, 64);
            float w0 = __shfl(wmine, sl0, 64);
            float w1 = __shfl(wmine, sl0 + 4, 64);
            float w2 = __shfl(wmine, sl0 + 8, 64);
            float w3 = __shfl(wmine, sl0 + 12, 64);
            ushort4 f0 = *reinterpret_cast<const ushort4*>(featb + (size_t)s0 * FDIM + lane * 4);
            ushort4 f1 = *reinterpret_cast<const ushort4*>(featb + (size_t)s1 * FDIM + lane * 4);
            ushort4 f2 = *reinterpret_cast<const ushort4*>(featb + (size_t)s2 * FDIM + lane * 4);
            ushort4 f3 = *reinterpret_cast<const ushort4*>(featb + (size_t)s3 * FDIM + lane * 4);
            a0.x = fmaf(w0, bf2f(f0.x), a0.x); a0.y = fmaf(w0, bf2f(f0.y), a0.y);
            a0.z = fmaf(w0, bf2f(f0.z), a0.z); a0.w = fmaf(w0, bf2f(f0.w), a0.w);
            a1.x = fmaf(w1, bf2f(f1.x), a1.x); a1.y = fmaf(w1, bf2f(f1.y), a1.y);
            a1.z = fmaf(w1, bf2f(f1.z), a1.z); a1.w = fmaf(w1, bf2f(f1.w), a1.w);
            a2.x = fmaf(w2, bf2f(f2.x), a2.x); a2.y = fmaf(w2, bf2f(f2.y), a2.y);
            a2.z = fmaf(w2, bf2f(f2.z), a2.z); a2.w = fmaf(w2, bf2f(f2.w), a2.w);
            a3.x = fmaf(w3, bf2f(f3.x), a3.x); a3.y = fmaf(w3, bf2f(f3.y), a3.y);
            a3.z = fmaf(w3, bf2f(f3.z), a3.z); a3.w = fmaf(w3, bf2f(f3.w), a3.w);
        }
        for (; j < jmax; ++j) {
            int sl = 4 * j + head;
            int s0 = __shfl(smine, sl, 64);
            float w0 = __shfl(wmine, sl, 64);
            ushort4 f0 = *reinterpret_cast<const ushort4*>(featb + (size_t)s0 * FDIM + lane * 4);
            a0.x = fmaf(w0, bf2f(f0.x), a0.x); a0.y = fmaf(w0, bf2f(f0.y), a0.y);
            a0.z = fmaf(w0, bf2f(f0.z), a0.z); a0.w = fmaf(w0, bf2f(f0.w), a0.w);
        }
    }
    float4 acc = make_float4(a0.x + a1.x + a2.x + a3.x, a0.y + a1.y + a2.y + a3.y,
                             a0.z + a1.z + a2.z + a3.z, a0.w + a1.w + a2.w + a3.w);

    if (resid_h) {
        ushort4 rh = *reinterpret_cast<const ushort4*>(resid_h + (size_t)node * FDIM + lane * 4);
        ushort4 rl = *reinterpret_cast<const ushort4*>(resid_l + (size_t)node * FDIM + lane * 4);
        acc.x += bf2f(rh.x) + bf2f(rl.x);
        acc.y += bf2f(rh.y) + bf2f(rl.y);
        acc.z += bf2f(rh.z) + bf2f(rl.z);
        acc.w += bf2f(rh.w) + bf2f(rl.w);
    }
    acc.x = acc.x > 0.f ? acc.x : expm1f(acc.x);
    acc.y = acc.y > 0.f ? acc.y : expm1f(acc.y);
    acc.z = acc.z > 0.f ? acc.z : expm1f(acc.z);
    acc.w = acc.w > 0.f ? acc.w : expm1f(acc.w);

    if (outf) {
        *reinterpret_cast<float4*>(outf + (size_t)node * FDIM + lane * 4) = acc;
    } else {
        unsigned h0 = f2bf_rne(acc.x), h1 = f2bf_rne(acc.y), h2 = f2bf_rne(acc.z), h3 = f2bf_rne(acc.w);
        *reinterpret_cast<ushort4*>(outh + (size_t)node * FDIM + lane * 4) =
            make_ushort4((ushort)h0, (ushort)h1, (ushort)h2, (ushort)h3);
        *reinterpret_cast<ushort4*>(outl + (size_t)node * FDIM + lane * 4) = make_ushort4(
            (ushort)(__float_as_uint(acc.x - bf2f(h0)) >> 16),
            (ushort)(__float_as_uint(acc.y - bf2f(h1)) >> 16),
            (ushort)(__float_as_uint(acc.z - bf2f(h2)) >> 16),
            (ushort)(__float_as_uint(acc.w - bf2f(h3)) >> 16));
    }
}

// ---------------- launch ----------------
extern "C" void kernel_launch(void* const* d_in, const int* in_sizes, int n_in,
                              void* d_out, int out_size, void* d_ws, size_t ws_size,
                              hipStream_t stream) {
    const float* features = (const float*)d_in[0];
    const int*   src      = (const int*)d_in[1];
    const int*   dst      = (const int*)d_in[2];
    const float* W1       = (const float*)d_in[3];
    const float* al1      = (const float*)d_in[4];
    const float* ar1      = (const float*)d_in[5];
    const float* W2       = (const float*)d_in[6];
    const float* al2      = (const float*)d_in[7];
    const float* ar2      = (const float*)d_in[8];
    float* out = (float*)d_out;

    const int N = N_NODES, E = N_EDGES;

    char* ws = (char*)d_ws;
    size_t off = 0;
    auto alloc = [&](size_t bytes) -> void* {
        void* p = ws + off;
        off = (off + bytes + 255) & ~(size_t)255;
        return p;
    };
    ushort* featb  = (ushort*)alloc((size_t)N * FDIM * 2);
    ushort* Afh    = (ushort*)alloc((size_t)N * FDIM * 2);   // layer-1 output hi (agg1 out)
    ushort* Afl    = (ushort*)alloc((size_t)N * FDIM * 2);   // layer-1 output lo (residual only)
    float*  el     = (float*)alloc((size_t)N * NHEAD * 4);
    float*  er     = (float*)alloc((size_t)N * NHEAD * 4);
    int*    rowptr = (int*)alloc((size_t)(N + 1) * 4);
    int*    cnt    = (int*)alloc((size_t)N * 4);
    int*    cursor = (int*)alloc((size_t)N * 4);
    int*    partial= (int*)alloc((size_t)N * 4);
    int*    bsum   = (int*)alloc((size_t)NSCAN * 4);
    int*    boff   = (int*)alloc((size_t)NSCAN * 4);
    int*    srcs   = (int*)alloc((size_t)E * 4);
    ushort* Bt1    = (ushort*)alloc((size_t)256 * 256 * 2);
    ushort* Bt2    = (ushort*)alloc((size_t)256 * 256 * 2);

    const int egrid = (E + 255) / 256;
    const int ngrid4 = (N + 3) / 4;

    // ---- CSR build (by dst) ----
    hipMemsetAsync(cnt, 0, (size_t)N * 4, stream);
    degree_kernel<<<egrid, 256, 0, stream>>>(dst, cnt, E);
    scan1_kernel<<<NSCAN, SCANB, 0, stream>>>(cnt, partial, bsum, N);
    scan2_kernel<<<1, 64, 0, stream>>>(bsum, boff, NSCAN);
    scan3_kernel<<<NSCAN, SCANB, 0, stream>>>(partial, boff, rowptr, cursor, N);
    scatter_kernel<<<egrid, 256, 0, stream>>>(src, dst, cursor, srcs, E);

    // ---- W conversion for both layers (one dispatch) ----
    bconv_kernel<<<dim3(16, 2), 256, 0, stream>>>(W1, W2, Bt1, Bt2);

    dim3 ggrid((N + 127) / 128, 2);

    // ---- layer 1 (A = fp32 features, rounded inline; el/er fused in epilogue) ----
    gemm_mfma_kernel<1><<<ggrid, 256, 0, stream>>>(features, nullptr, Bt1, featb,
                                                   al1, ar1, el, er, N);
    agg_kernel<<<ngrid4, 256, 0, stream>>>(featb, el, er, rowptr, srcs,
                                           nullptr, nullptr, nullptr, Afh, Afl, N);

    // ---- layer 2 (A = layer-1 output hi; residual = hi+lo) ----
    gemm_mfma_kernel<0><<<ggrid, 256, 0, stream>>>(nullptr, Afh, Bt2, featb,
                                                   al2, ar2, el, er, N);
    agg_kernel<<<ngrid4, 256, 0, stream>>>(featb, el, er, rowptr, srcs,
                                           Afh, Afl, out, nullptr, nullptr, N);
}

// Round 10
// 290.995 us; speedup vs baseline: 1.1604x; 1.0462x over previous
//
#include <hip/hip_runtime.h>
#include <hip/hip_bf16.h>

#define N_NODES 50000
#define N_EDGES 800000
#define NHEAD 4
#define DHEAD 64
#define FDIM 256   // NHEAD*DHEAD == in_feats == out_feats
#define SCANB 1024
#define NSCAN ((N_NODES + SCANB - 1) / SCANB)   // 49

typedef __attribute__((ext_vector_type(8))) short bfrag8;   // 8 bf16 (4 VGPRs)
typedef __attribute__((ext_vector_type(4))) float f32x4;    // 4 fp32 acc

// ---------------- bf16 helpers ----------------
__device__ __forceinline__ unsigned f2bf_rne(float x) {
    unsigned u = __float_as_uint(x);
    return (u + 0x7fffu + ((u >> 16) & 1u)) >> 16;
}
__device__ __forceinline__ float bf2f(unsigned u) {
    return __uint_as_float(u << 16);
}

// ---------------- CSR build ----------------
__global__ void degree_kernel(const int* __restrict__ dst, int* __restrict__ cnt, int E) {
    int e = blockIdx.x * 256 + threadIdx.x;
    if (e < E) atomicAdd(&cnt[dst[e]], 1);
}

__global__ __launch_bounds__(1024) void scan1_kernel(const int* __restrict__ cnt,
                                                     int* __restrict__ partial,
                                                     int* __restrict__ bsum, int N) {
    __shared__ int sdata[SCANB];
    int i = blockIdx.x * SCANB + (int)threadIdx.x;
    int v = (i < N) ? cnt[i] : 0;
    sdata[threadIdx.x] = v;
    __syncthreads();
    for (int off = 1; off < SCANB; off <<= 1) {
        int t = (threadIdx.x >= (unsigned)off) ? sdata[threadIdx.x - off] : 0;
        __syncthreads();
        sdata[threadIdx.x] += t;
        __syncthreads();
    }
    if (i < N) partial[i] = sdata[threadIdx.x];
    if (threadIdx.x == SCANB - 1) bsum[blockIdx.x] = sdata[SCANB - 1];
}

// scan3 with scan2 folded in: each block sums its predecessor block-sums (<=64).
__global__ __launch_bounds__(1024) void scan3_kernel(const int* __restrict__ partial,
                                                     const int* __restrict__ bsum,
                                                     int* __restrict__ rowptr,
                                                     int* __restrict__ cursor, int N) {
    __shared__ int boff_s;
    if (threadIdx.x < 64) {
        int v = ((int)threadIdx.x < (int)blockIdx.x) ? bsum[threadIdx.x] : 0;
#pragma unroll
        for (int off = 1; off < 64; off <<= 1) v += __shfl_xor(v, off, 64);
        if (threadIdx.x == 0) boff_s = v;
    }
    __syncthreads();
    int i = blockIdx.x * SCANB + (int)threadIdx.x;
    if (i < N) {
        int inc = partial[i] + boff_s;
        rowptr[i + 1] = inc;
        if (i + 1 < N) cursor[i + 1] = inc;
    }
    if (i == 0) { rowptr[0] = 0; cursor[0] = 0; }
}

__global__ void scatter_kernel(const int* __restrict__ src, const int* __restrict__ dst,
                               int* __restrict__ cursor, int* __restrict__ srcs, int E) {
    int e = blockIdx.x * 256 + threadIdx.x;
    if (e < E) {
        int pos = atomicAdd(&cursor[dst[e]], 1);
        srcs[pos] = src[e];
    }
}

// ---------------- W round+transpose (both layers, one dispatch) ----------------
__global__ __launch_bounds__(256) void bconv_kernel(const float* __restrict__ B1,
                                                    const float* __restrict__ B2,
                                                    ushort* __restrict__ Bt1,
                                                    ushort* __restrict__ Bt2) {
    const float* B = blockIdx.y ? B2 : B1;
    ushort* Bt = blockIdx.y ? Bt2 : Bt1;
    __shared__ ushort th[16][264];
    int k0 = blockIdx.x * 16;
    int n = threadIdx.x;
#pragma unroll
    for (int k = 0; k < 16; ++k)
        th[k][n] = (ushort)f2bf_rne(B[(size_t)(k0 + k) * 256 + n]);
    __syncthreads();
    ushort oh[16];
#pragma unroll
    for (int k = 0; k < 16; ++k) oh[k] = th[k][n];
#pragma unroll
    for (int q = 0; q < 4; ++q)
        *reinterpret_cast<ushort4*>(Bt + (size_t)n * 256 + k0 + q * 4) =
            make_ushort4(oh[q*4+0], oh[q*4+1], oh[q*4+2], oh[q*4+3]);
}

// ---------------- GEMM + fused el/er epilogue (1-pass bf16 MFMA) ----------------
template <int SPLITA>
__global__ __launch_bounds__(256) void gemm_mfma_kernel(const float* __restrict__ Af,
                                                        const ushort* __restrict__ Ahg,
                                                        const ushort* __restrict__ Bt,
                                                        ushort* __restrict__ Cb,
                                                        const float* __restrict__ al,
                                                        const float* __restrict__ ar,
                                                        float* __restrict__ el,
                                                        float* __restrict__ er, int M) {
    __shared__ ushort Ah[128][40];   // [m][k], 80B row stride (bank-spread)
    __shared__ ushort Bh[128][40];   // [n][k]
    const int t = threadIdx.x;
    const int lane = t & 63, wave = t >> 6;
    const int wr = wave >> 1, wc = wave & 1;
    const int row0 = blockIdx.x * 128;
    const int col0 = blockIdx.y * 128;

    f32x4 acc[4][4];
#pragma unroll
    for (int i = 0; i < 4; ++i)
#pragma unroll
        for (int j = 0; j < 4; ++j) { acc[i][j].x = 0.f; acc[i][j].y = 0.f; acc[i][j].z = 0.f; acc[i][j].w = 0.f; }

    const int srow = t >> 1;            // 0..127
    const int skoff = (t & 1) * 16;     // 0 or 16
    int arow = row0 + srow; if (arow >= M) arow = M - 1;   // clamp; stores guarded
    const size_t abase = (size_t)arow * 256 + skoff;
    const size_t bbase = (size_t)(col0 + srow) * 256 + skoff;

    float4 af0, af1, af2, af3;          // SPLITA: 16 fp32 of A
    uint4 r0, r1;                       // !SPLITA: Ah 16B x2
    uint4 r4, r5;                       // B

#define LOADK(kk)                                                              \
    do {                                                                       \
        if constexpr (SPLITA) {                                                \
            const float4* pa = reinterpret_cast<const float4*>(Af + abase + (kk)); \
            af0 = pa[0]; af1 = pa[1]; af2 = pa[2]; af3 = pa[3];                \
        } else {                                                               \
            r0 = *reinterpret_cast<const uint4*>(Ahg + abase + (kk));          \
            r1 = *reinterpret_cast<const uint4*>(Ahg + abase + (kk) + 8);      \
        }                                                                      \
        r4 = *reinterpret_cast<const uint4*>(Bt + bbase + (kk));               \
        r5 = *reinterpret_cast<const uint4*>(Bt + bbase + (kk) + 8);           \
    } while (0)

    LOADK(0);
#pragma unroll
    for (int kk = 0; kk < 256; kk += 32) {
        if (kk) __syncthreads();
        if constexpr (SPLITA) {
            float v[16];
            v[0]=af0.x; v[1]=af0.y; v[2]=af0.z; v[3]=af0.w;
            v[4]=af1.x; v[5]=af1.y; v[6]=af1.z; v[7]=af1.w;
            v[8]=af2.x; v[9]=af2.y; v[10]=af2.z; v[11]=af2.w;
            v[12]=af3.x; v[13]=af3.y; v[14]=af3.z; v[15]=af3.w;
            ushort hh[16];
#pragma unroll
            for (int q = 0; q < 16; ++q) hh[q] = (ushort)f2bf_rne(v[q]);
#pragma unroll
            for (int q = 0; q < 4; ++q)
                *reinterpret_cast<ushort4*>(&Ah[srow][skoff + q * 4]) =
                    make_ushort4(hh[q*4+0], hh[q*4+1], hh[q*4+2], hh[q*4+3]);
        } else {
            *reinterpret_cast<uint4*>(&Ah[srow][skoff])     = r0;
            *reinterpret_cast<uint4*>(&Ah[srow][skoff + 8]) = r1;
        }
        *reinterpret_cast<uint4*>(&Bh[srow][skoff])     = r4;
        *reinterpret_cast<uint4*>(&Bh[srow][skoff + 8]) = r5;
        __syncthreads();
        if (kk + 32 < 256) LOADK(kk + 32);   // latency hides under MFMA below

        const int kg = (lane >> 4) * 8;
        const int rsel = lane & 15;
        bfrag8 afh[4], bfh[4];
#pragma unroll
        for (int i = 0; i < 4; ++i)
            afh[i] = *reinterpret_cast<const bfrag8*>(&Ah[wr * 64 + i * 16 + rsel][kg]);
#pragma unroll
        for (int j = 0; j < 4; ++j)
            bfh[j] = *reinterpret_cast<const bfrag8*>(&Bh[wc * 64 + j * 16 + rsel][kg]);
#pragma unroll
        for (int i = 0; i < 4; ++i)
#pragma unroll
            for (int j = 0; j < 4; ++j)
                acc[i][j] = __builtin_amdgcn_mfma_f32_16x16x32_bf16(afh[i], bfh[j], acc[i][j], 0, 0, 0);
    }
#undef LOADK

    // ---- epilogue: C store + fused el/er ----
    const int ccol = lane & 15;
    const int crow = (lane >> 4) * 4;
    const int head = (col0 >> 6) + wc;   // this wave's head (disjoint across by/wc)
    float alv[4], arv[4];
#pragma unroll
    for (int j = 0; j < 4; ++j) {
        alv[j] = al[head * 64 + j * 16 + ccol];
        arv[j] = ar[head * 64 + j * 16 + ccol];
    }
#pragma unroll
    for (int i = 0; i < 4; ++i) {
#pragma unroll
        for (int r = 0; r < 4; ++r) {
            int row = row0 + wr * 64 + i * 16 + crow + r;
            float vj[4];
#pragma unroll
            for (int j = 0; j < 4; ++j)
                vj[j] = (r == 0) ? acc[i][j].x : (r == 1) ? acc[i][j].y : (r == 2) ? acc[i][j].z : acc[i][j].w;
            float pl = 0.f, pr = 0.f;
#pragma unroll
            for (int j = 0; j < 4; ++j) {
                pl = fmaf(vj[j], alv[j], pl);
                pr = fmaf(vj[j], arv[j], pr);
            }
#pragma unroll
            for (int msk = 1; msk < 16; msk <<= 1) {
                pl += __shfl_xor(pl, msk, 64);
                pr += __shfl_xor(pr, msk, 64);
            }
            if (row < M) {
                if (ccol == 0) {
                    el[(size_t)row * NHEAD + head] = pl;
                    er[(size_t)row * NHEAD + head] = pr;
                }
#pragma unroll
                for (int j = 0; j < 4; ++j) {
                    int col = col0 + wc * 64 + j * 16 + ccol;
                    Cb[(size_t)row * 256 + col] = (ushort)f2bf_rne(vj[j]);
                }
            }
        }
    }
}

// ---------------- fused softmax + aggregation: SINGLE edge pass ----------------
// No max subtraction (|x| <~ 20 << 87, fp32 exp safe; softmax is shift-invariant).
// Each lane owns (edge eo = lane>>2, head h4 = lane&3): computes exp once.
// Gather ladder uses shuffle-broadcast unnormalized weights; denominator
// accumulated in the same pass; normalize at the end (before residual).
__global__ __launch_bounds__(256) void agg_kernel(
        const ushort* __restrict__ featb, const float* __restrict__ el,
        const float* __restrict__ er, const int* __restrict__ rowptr,
        const int* __restrict__ srcs, const ushort* __restrict__ resid,
        float* __restrict__ outf, ushort* __restrict__ outh, int N) {
    int node = blockIdx.x * 4 + (threadIdx.x >> 6);
    if (node >= N) return;
    int lane = threadIdx.x & 63;
    int h4 = lane & 3;        // head for weights
    int eo = lane >> 2;       // edge slot within 16-chunk
    int head = lane >> 4;     // head for gather (feature layout)
    float erh = er[(size_t)node * NHEAD + h4];
    int beg = rowptr[node], end = rowptr[node + 1];

    float wsum = 0.f;
    f32x4 a0 = {0.f, 0.f, 0.f, 0.f}, a1 = a0, a2 = a0, a3 = a0;
    for (int base = beg; base < end; base += 16) {
        int p = base + eo;
        int smine = 0;
        float wmine = 0.f;
        if (p < end) {
            smine = srcs[p];
            float t = el[(size_t)smine * NHEAD + h4] + erh;
            t = t > 0.f ? t : 0.2f * t;
            wmine = __expf(t);
        }
        wsum += wmine;
        int jmax = end - base; if (jmax > 16) jmax = 16;   // wave-uniform bound
        int j = 0;
        for (; j + 3 < jmax; j += 4) {
            int sl0 = 4 * j + head;
            int s0 = __shfl(smine, sl0, 64);
            int s1 = __shfl(smine, sl0 + 4, 64);
            int s2 = __shfl(smine, sl0 + 8, 64);
            int s3 = __shfl(smine, sl0 + 12, 64);
            float w0 = __shfl(wmine, sl0, 64);
            float w1 = __shfl(wmine, sl0 + 4, 64);
            float w2 = __shfl(wmine, sl0 + 8, 64);
            float w3 = __shfl(wmine, sl0 + 12, 64);
            ushort4 f0 = *reinterpret_cast<const ushort4*>(featb + (size_t)s0 * FDIM + lane * 4);
            ushort4 f1 = *reinterpret_cast<const ushort4*>(featb + (size_t)s1 * FDIM + lane * 4);
            ushort4 f2 = *reinterpret_cast<const ushort4*>(featb + (size_t)s2 * FDIM + lane * 4);
            ushort4 f3 = *reinterpret_cast<const ushort4*>(featb + (size_t)s3 * FDIM + lane * 4);
            a0.x = fmaf(w0, bf2f(f0.x), a0.x); a0.y = fmaf(w0, bf2f(f0.y), a0.y);
            a0.z = fmaf(w0, bf2f(f0.z), a0.z); a0.w = fmaf(w0, bf2f(f0.w), a0.w);
            a1.x = fmaf(w1, bf2f(f1.x), a1.x); a1.y = fmaf(w1, bf2f(f1.y), a1.y);
            a1.z = fmaf(w1, bf2f(f1.z), a1.z); a1.w = fmaf(w1, bf2f(f1.w), a1.w);
            a2.x = fmaf(w2, bf2f(f2.x), a2.x); a2.y = fmaf(w2, bf2f(f2.y), a2.y);
            a2.z = fmaf(w2, bf2f(f2.z), a2.z); a2.w = fmaf(w2, bf2f(f2.w), a2.w);
            a3.x = fmaf(w3, bf2f(f3.x), a3.x); a3.y = fmaf(w3, bf2f(f3.y), a3.y);
            a3.z = fmaf(w3, bf2f(f3.z), a3.z); a3.w = fmaf(w3, bf2f(f3.w), a3.w);
        }
        for (; j < jmax; ++j) {
            int sl = 4 * j + head;
            int s0 = __shfl(smine, sl, 64);
            float w0 = __shfl(wmine, sl, 64);
            ushort4 f0 = *reinterpret_cast<const ushort4*>(featb + (size_t)s0 * FDIM + lane * 4);
            a0.x = fmaf(w0, bf2f(f0.x), a0.x); a0.y = fmaf(w0, bf2f(f0.y), a0.y);
            a0.z = fmaf(w0, bf2f(f0.z), a0.z); a0.w = fmaf(w0, bf2f(f0.w), a0.w);
        }
    }
    // denom: reduce over the 16 lanes sharing h4, then pick this lane's head
    wsum += __shfl_xor(wsum, 4, 64);
    wsum += __shfl_xor(wsum, 8, 64);
    wsum += __shfl_xor(wsum, 16, 64);
    wsum += __shfl_xor(wsum, 32, 64);
    float denom = __shfl(wsum, head, 64);   // lane 'head' (0..3) holds h4==head
    float dinv = denom > 0.f ? 1.0f / denom : 0.f;

    float4 acc = make_float4((a0.x + a1.x + a2.x + a3.x) * dinv,
                             (a0.y + a1.y + a2.y + a3.y) * dinv,
                             (a0.z + a1.z + a2.z + a3.z) * dinv,
                             (a0.w + a1.w + a2.w + a3.w) * dinv);

    if (resid) {
        ushort4 rh = *reinterpret_cast<const ushort4*>(resid + (size_t)node * FDIM + lane * 4);
        acc.x += bf2f(rh.x);
        acc.y += bf2f(rh.y);
        acc.z += bf2f(rh.z);
        acc.w += bf2f(rh.w);
    }
    acc.x = acc.x > 0.f ? acc.x : expm1f(acc.x);
    acc.y = acc.y > 0.f ? acc.y : expm1f(acc.y);
    acc.z = acc.z > 0.f ? acc.z : expm1f(acc.z);
    acc.w = acc.w > 0.f ? acc.w : expm1f(acc.w);

    if (outf) {
        *reinterpret_cast<float4*>(outf + (size_t)node * FDIM + lane * 4) = acc;
    } else {
        *reinterpret_cast<ushort4*>(outh + (size_t)node * FDIM + lane * 4) =
            make_ushort4((ushort)f2bf_rne(acc.x), (ushort)f2bf_rne(acc.y),
                         (ushort)f2bf_rne(acc.z), (ushort)f2bf_rne(acc.w));
    }
}

// ---------------- launch ----------------
extern "C" void kernel_launch(void* const* d_in, const int* in_sizes, int n_in,
                              void* d_out, int out_size, void* d_ws, size_t ws_size,
                              hipStream_t stream) {
    const float* features = (const float*)d_in[0];
    const int*   src      = (const int*)d_in[1];
    const int*   dst      = (const int*)d_in[2];
    const float* W1       = (const float*)d_in[3];
    const float* al1      = (const float*)d_in[4];
    const float* ar1      = (const float*)d_in[5];
    const float* W2       = (const float*)d_in[6];
    const float* al2      = (const float*)d_in[7];
    const float* ar2      = (const float*)d_in[8];
    float* out = (float*)d_out;

    const int N = N_NODES, E = N_EDGES;

    char* ws = (char*)d_ws;
    size_t off = 0;
    auto alloc = [&](size_t bytes) -> void* {
        void* p = ws + off;
        off = (off + bytes + 255) & ~(size_t)255;
        return p;
    };
    ushort* featb  = (ushort*)alloc((size_t)N * FDIM * 2);
    ushort* Afh    = (ushort*)alloc((size_t)N * FDIM * 2);   // layer-1 output (agg1 out, bf16)
    float*  el     = (float*)alloc((size_t)N * NHEAD * 4);
    float*  er     = (float*)alloc((size_t)N * NHEAD * 4);
    int*    rowptr = (int*)alloc((size_t)(N + 1) * 4);
    int*    cnt    = (int*)alloc((size_t)N * 4);
    int*    cursor = (int*)alloc((size_t)N * 4);
    int*    partial= (int*)alloc((size_t)N * 4);
    int*    bsum   = (int*)alloc((size_t)NSCAN * 4);
    int*    srcs   = (int*)alloc((size_t)E * 4);
    ushort* Bt1    = (ushort*)alloc((size_t)256 * 256 * 2);
    ushort* Bt2    = (ushort*)alloc((size_t)256 * 256 * 2);

    const int egrid = (E + 255) / 256;
    const int ngrid4 = (N + 3) / 4;

    // ---- CSR build (by dst) ----
    hipMemsetAsync(cnt, 0, (size_t)N * 4, stream);
    degree_kernel<<<egrid, 256, 0, stream>>>(dst, cnt, E);
    scan1_kernel<<<NSCAN, SCANB, 0, stream>>>(cnt, partial, bsum, N);
    scan3_kernel<<<NSCAN, SCANB, 0, stream>>>(partial, bsum, rowptr, cursor, N);
    scatter_kernel<<<egrid, 256, 0, stream>>>(src, dst, cursor, srcs, E);

    // ---- W conversion for both layers (one dispatch) ----
    bconv_kernel<<<dim3(16, 2), 256, 0, stream>>>(W1, W2, Bt1, Bt2);

    dim3 ggrid((N + 127) / 128, 2);

    // ---- layer 1 (A = fp32 features, rounded inline; el/er fused in epilogue) ----
    gemm_mfma_kernel<1><<<ggrid, 256, 0, stream>>>(features, nullptr, Bt1, featb,
                                                   al1, ar1, el, er, N);
    agg_kernel<<<ngrid4, 256, 0, stream>>>(featb, el, er, rowptr, srcs,
                                           nullptr, nullptr, Afh, N);

    // ---- layer 2 (A = layer-1 output bf16; residual = same, bf16) ----
    gemm_mfma_kernel<0><<<ggrid, 256, 0, stream>>>(nullptr, Afh, Bt2, featb,
                                                   al2, ar2, el, er, N);
    agg_kernel<<<ngrid4, 256, 0, stream>>>(featb, el, er, rowptr, srcs,
                                           Afh, out, nullptr, N);
}

// Round 11
// 283.659 us; speedup vs baseline: 1.1904x; 1.0259x over previous
//
#include <hip/hip_runtime.h>
#include <hip/hip_bf16.h>

#define N_NODES 50000
#define N_EDGES 800000
#define NHEAD 4
#define DHEAD 64
#define FDIM 256   // NHEAD*DHEAD == in_feats == out_feats
#define SCANB 1024
#define NSCAN ((N_NODES + SCANB - 1) / SCANB)   // 49

typedef __attribute__((ext_vector_type(8))) short bfrag8;   // 8 bf16 (4 VGPRs)
typedef __attribute__((ext_vector_type(4))) float f32x4;    // 4 fp32 acc

// ---------------- bf16 helpers ----------------
__device__ __forceinline__ unsigned f2bf_rne(float x) {
    unsigned u = __float_as_uint(x);
    return (u + 0x7fffu + ((u >> 16) & 1u)) >> 16;
}
__device__ __forceinline__ float bf2f(unsigned u) {
    return __uint_as_float(u << 16);
}

// ---------------- CSR build ----------------
__global__ void degree_kernel(const int* __restrict__ dst, int* __restrict__ cnt, int E) {
    int e = blockIdx.x * 256 + threadIdx.x;
    if (e < E) atomicAdd(&cnt[dst[e]], 1);
}

__global__ __launch_bounds__(1024) void scan1_kernel(const int* __restrict__ cnt,
                                                     int* __restrict__ partial,
                                                     int* __restrict__ bsum, int N) {
    __shared__ int sdata[SCANB];
    int i = blockIdx.x * SCANB + (int)threadIdx.x;
    int v = (i < N) ? cnt[i] : 0;
    sdata[threadIdx.x] = v;
    __syncthreads();
    for (int off = 1; off < SCANB; off <<= 1) {
        int t = (threadIdx.x >= (unsigned)off) ? sdata[threadIdx.x - off] : 0;
        __syncthreads();
        sdata[threadIdx.x] += t;
        __syncthreads();
    }
    if (i < N) partial[i] = sdata[threadIdx.x];
    if (threadIdx.x == SCANB - 1) bsum[blockIdx.x] = sdata[SCANB - 1];
}

// scan3 with scan2 folded in: each block sums its predecessor block-sums (<=64).
__global__ __launch_bounds__(1024) void scan3_kernel(const int* __restrict__ partial,
                                                     const int* __restrict__ bsum,
                                                     int* __restrict__ rowptr,
                                                     int* __restrict__ cursor, int N) {
    __shared__ int boff_s;
    if (threadIdx.x < 64) {
        int v = ((int)threadIdx.x < (int)blockIdx.x) ? bsum[threadIdx.x] : 0;
#pragma unroll
        for (int off = 1; off < 64; off <<= 1) v += __shfl_xor(v, off, 64);
        if (threadIdx.x == 0) boff_s = v;
    }
    __syncthreads();
    int i = blockIdx.x * SCANB + (int)threadIdx.x;
    if (i < N) {
        int inc = partial[i] + boff_s;
        rowptr[i + 1] = inc;
        if (i + 1 < N) cursor[i + 1] = inc;
    }
    if (i == 0) { rowptr[0] = 0; cursor[0] = 0; }
}

__global__ void scatter_kernel(const int* __restrict__ src, const int* __restrict__ dst,
                               int* __restrict__ cursor, int* __restrict__ srcs, int E) {
    int e = blockIdx.x * 256 + threadIdx.x;
    if (e < E) {
        int pos = atomicAdd(&cursor[dst[e]], 1);
        srcs[pos] = src[e];
    }
}

// ---------------- W round+transpose (both layers, one dispatch) ----------------
__global__ __launch_bounds__(256) void bconv_kernel(const float* __restrict__ B1,
                                                    const float* __restrict__ B2,
                                                    ushort* __restrict__ Bt1,
                                                    ushort* __restrict__ Bt2) {
    const float* B = blockIdx.y ? B2 : B1;
    ushort* Bt = blockIdx.y ? Bt2 : Bt1;
    __shared__ ushort th[16][264];
    int k0 = blockIdx.x * 16;
    int n = threadIdx.x;
#pragma unroll
    for (int k = 0; k < 16; ++k)
        th[k][n] = (ushort)f2bf_rne(B[(size_t)(k0 + k) * 256 + n]);
    __syncthreads();
    ushort oh[16];
#pragma unroll
    for (int k = 0; k < 16; ++k) oh[k] = th[k][n];
#pragma unroll
    for (int q = 0; q < 4; ++q)
        *reinterpret_cast<ushort4*>(Bt + (size_t)n * 256 + k0 + q * 4) =
            make_ushort4(oh[q*4+0], oh[q*4+1], oh[q*4+2], oh[q*4+3]);
}

// ---------------- GEMM + fused el/er epilogue (BM=128, BN=256, 8 waves) ----------------
// A read exactly once (full output width per block). Wave (wr,wc): wr=wave>>2 M-half,
// wc=wave&3 N-quarter = exactly one head. acc[4][4] per wave (same as 2-col version).
template <int SPLITA>
__global__ __launch_bounds__(512) void gemm_mfma_kernel(const float* __restrict__ Af,
                                                        const ushort* __restrict__ Ahg,
                                                        const ushort* __restrict__ Bt,
                                                        ushort* __restrict__ Cb,
                                                        const float* __restrict__ al,
                                                        const float* __restrict__ ar,
                                                        float* __restrict__ el,
                                                        float* __restrict__ er, int M) {
    __shared__ ushort Ah[128][40];   // [m][k], 80B row stride (bank-spread)
    __shared__ ushort Bh[256][40];   // [n][k]
    const int t = threadIdx.x;
    const int lane = t & 63, wave = t >> 6;   // 0..7
    const int wr = wave >> 2, wc = wave & 3;
    const int row0 = blockIdx.x * 128;

    f32x4 acc[4][4];
#pragma unroll
    for (int i = 0; i < 4; ++i)
#pragma unroll
        for (int j = 0; j < 4; ++j) { acc[i][j].x = 0.f; acc[i][j].y = 0.f; acc[i][j].z = 0.f; acc[i][j].w = 0.f; }

    // staging: A row = t>>2 (4 thr/row, 8 k each); B row n = t>>1 (2 thr/row, 16 k each)
    const int arow_l = t >> 2;
    const int akoff = (t & 3) * 8;
    int arow = row0 + arow_l; if (arow >= M) arow = M - 1;   // clamp; stores guarded
    const size_t abase = (size_t)arow * 256 + akoff;
    const int brow = t >> 1;
    const int bkoff = (t & 1) * 16;
    const size_t bbase = (size_t)brow * 256 + bkoff;

    float4 af0, af1;                     // SPLITA: 8 fp32 of A
    uint4 r0;                            // !SPLITA: 8 bf16 of A
    uint4 r4, r5;                        // 16 bf16 of B

#define LOADK(kk)                                                              \
    do {                                                                       \
        if constexpr (SPLITA) {                                                \
            const float4* pa = reinterpret_cast<const float4*>(Af + abase + (kk)); \
            af0 = pa[0]; af1 = pa[1];                                          \
        } else {                                                               \
            r0 = *reinterpret_cast<const uint4*>(Ahg + abase + (kk));          \
        }                                                                      \
        r4 = *reinterpret_cast<const uint4*>(Bt + bbase + (kk));               \
        r5 = *reinterpret_cast<const uint4*>(Bt + bbase + (kk) + 8);           \
    } while (0)

    LOADK(0);
#pragma unroll
    for (int kk = 0; kk < 256; kk += 32) {
        if (kk) __syncthreads();
        if constexpr (SPLITA) {
            float v[8] = {af0.x, af0.y, af0.z, af0.w, af1.x, af1.y, af1.z, af1.w};
            ushort hh[8];
#pragma unroll
            for (int q = 0; q < 8; ++q) hh[q] = (ushort)f2bf_rne(v[q]);
            *reinterpret_cast<ushort4*>(&Ah[arow_l][akoff]) =
                make_ushort4(hh[0], hh[1], hh[2], hh[3]);
            *reinterpret_cast<ushort4*>(&Ah[arow_l][akoff + 4]) =
                make_ushort4(hh[4], hh[5], hh[6], hh[7]);
        } else {
            *reinterpret_cast<uint4*>(&Ah[arow_l][akoff]) = r0;
        }
        *reinterpret_cast<uint4*>(&Bh[brow][bkoff])     = r4;
        *reinterpret_cast<uint4*>(&Bh[brow][bkoff + 8]) = r5;
        __syncthreads();
        if (kk + 32 < 256) LOADK(kk + 32);   // latency hides under MFMA below

        const int kg = (lane >> 4) * 8;
        const int rsel = lane & 15;
        bfrag8 afh[4], bfh[4];
#pragma unroll
        for (int i = 0; i < 4; ++i)
            afh[i] = *reinterpret_cast<const bfrag8*>(&Ah[wr * 64 + i * 16 + rsel][kg]);
#pragma unroll
        for (int j = 0; j < 4; ++j)
            bfh[j] = *reinterpret_cast<const bfrag8*>(&Bh[wc * 64 + j * 16 + rsel][kg]);
#pragma unroll
        for (int i = 0; i < 4; ++i)
#pragma unroll
            for (int j = 0; j < 4; ++j)
                acc[i][j] = __builtin_amdgcn_mfma_f32_16x16x32_bf16(afh[i], bfh[j], acc[i][j], 0, 0, 0);
    }
#undef LOADK

    // ---- epilogue: C store + fused el/er (this wave's head = wc) ----
    const int ccol = lane & 15;
    const int crow = (lane >> 4) * 4;
    const int head = wc;
    float alv[4], arv[4];
#pragma unroll
    for (int j = 0; j < 4; ++j) {
        alv[j] = al[head * 64 + j * 16 + ccol];
        arv[j] = ar[head * 64 + j * 16 + ccol];
    }
#pragma unroll
    for (int i = 0; i < 4; ++i) {
#pragma unroll
        for (int r = 0; r < 4; ++r) {
            int row = row0 + wr * 64 + i * 16 + crow + r;
            float vj[4];
#pragma unroll
            for (int j = 0; j < 4; ++j)
                vj[j] = (r == 0) ? acc[i][j].x : (r == 1) ? acc[i][j].y : (r == 2) ? acc[i][j].z : acc[i][j].w;
            float pl = 0.f, pr = 0.f;
#pragma unroll
            for (int j = 0; j < 4; ++j) {
                pl = fmaf(vj[j], alv[j], pl);
                pr = fmaf(vj[j], arv[j], pr);
            }
#pragma unroll
            for (int msk = 1; msk < 16; msk <<= 1) {
                pl += __shfl_xor(pl, msk, 64);
                pr += __shfl_xor(pr, msk, 64);
            }
            if (row < M) {
                if (ccol == 0) {
                    el[(size_t)row * NHEAD + head] = pl;
                    er[(size_t)row * NHEAD + head] = pr;
                }
#pragma unroll
                for (int j = 0; j < 4; ++j) {
                    int col = wc * 64 + j * 16 + ccol;
                    Cb[(size_t)row * 256 + col] = (ushort)f2bf_rne(vj[j]);
                }
            }
        }
    }
}

// ---------------- fused softmax + aggregation: SINGLE edge pass ----------------
__global__ __launch_bounds__(256) void agg_kernel(
        const ushort* __restrict__ featb, const float* __restrict__ el,
        const float* __restrict__ er, const int* __restrict__ rowptr,
        const int* __restrict__ srcs, const ushort* __restrict__ resid,
        float* __restrict__ outf, ushort* __restrict__ outh, int N) {
    int node = blockIdx.x * 4 + (threadIdx.x >> 6);
    if (node >= N) return;
    int lane = threadIdx.x & 63;
    int h4 = lane & 3;        // head for weights
    int eo = lane >> 2;       // edge slot within 16-chunk
    int head = lane >> 4;     // head for gather (feature layout)
    float erh = er[(size_t)node * NHEAD + h4];
    int beg = rowptr[node], end = rowptr[node + 1];

    float wsum = 0.f;
    f32x4 a0 = {0.f, 0.f, 0.f, 0.f}, a1 = a0, a2 = a0, a3 = a0;
    for (int base = beg; base < end; base += 16) {
        int p = base + eo;
        int smine = 0;
        float wmine = 0.f;
        if (p < end) {
            smine = srcs[p];
            float t = el[(size_t)smine * NHEAD + h4] + erh;
            t = t > 0.f ? t : 0.2f * t;
            wmine = __expf(t);
        }
        wsum += wmine;
        int jmax = end - base; if (jmax > 16) jmax = 16;   // wave-uniform bound
        int j = 0;
        for (; j + 3 < jmax; j += 4) {
            int sl0 = 4 * j + head;
            int s0 = __shfl(smine, sl0, 64);
            int s1 = __shfl(smine, sl0 + 4, 64);
            int s2 = __shfl(smine, sl0 + 8, 64);
            int s3 = __shfl(smine, sl0 + 12, 64);
            float w0 = __shfl(wmine, sl0, 64);
            float w1 = __shfl(wmine, sl0 + 4, 64);
            float w2 = __shfl(wmine, sl0 + 8, 64);
            float w3 = __shfl(wmine, sl0 + 12, 64);
            ushort4 f0 = *reinterpret_cast<const ushort4*>(featb + (size_t)s0 * FDIM + lane * 4);
            ushort4 f1 = *reinterpret_cast<const ushort4*>(featb + (size_t)s1 * FDIM + lane * 4);
            ushort4 f2 = *reinterpret_cast<const ushort4*>(featb + (size_t)s2 * FDIM + lane * 4);
            ushort4 f3 = *reinterpret_cast<const ushort4*>(featb + (size_t)s3 * FDIM + lane * 4);
            a0.x = fmaf(w0, bf2f(f0.x), a0.x); a0.y = fmaf(w0, bf2f(f0.y), a0.y);
            a0.z = fmaf(w0, bf2f(f0.z), a0.z); a0.w = fmaf(w0, bf2f(f0.w), a0.w);
            a1.x = fmaf(w1, bf2f(f1.x), a1.x); a1.y = fmaf(w1, bf2f(f1.y), a1.y);
            a1.z = fmaf(w1, bf2f(f1.z), a1.z); a1.w = fmaf(w1, bf2f(f1.w), a1.w);
            a2.x = fmaf(w2, bf2f(f2.x), a2.x); a2.y = fmaf(w2, bf2f(f2.y), a2.y);
            a2.z = fmaf(w2, bf2f(f2.z), a2.z); a2.w = fmaf(w2, bf2f(f2.w), a2.w);
            a3.x = fmaf(w3, bf2f(f3.x), a3.x); a3.y = fmaf(w3, bf2f(f3.y), a3.y);
            a3.z = fmaf(w3, bf2f(f3.z), a3.z); a3.w = fmaf(w3, bf2f(f3.w), a3.w);
        }
        for (; j < jmax; ++j) {
            int sl = 4 * j + head;
            int s0 = __shfl(smine, sl, 64);
            float w0 = __shfl(wmine, sl, 64);
            ushort4 f0 = *reinterpret_cast<const ushort4*>(featb + (size_t)s0 * FDIM + lane * 4);
            a0.x = fmaf(w0, bf2f(f0.x), a0.x); a0.y = fmaf(w0, bf2f(f0.y), a0.y);
            a0.z = fmaf(w0, bf2f(f0.z), a0.z); a0.w = fmaf(w0, bf2f(f0.w), a0.w);
        }
    }
    wsum += __shfl_xor(wsum, 4, 64);
    wsum += __shfl_xor(wsum, 8, 64);
    wsum += __shfl_xor(wsum, 16, 64);
    wsum += __shfl_xor(wsum, 32, 64);
    float denom = __shfl(wsum, head, 64);   // lane 'head' (0..3) holds h4==head
    float dinv = denom > 0.f ? 1.0f / denom : 0.f;

    float4 acc = make_float4((a0.x + a1.x + a2.x + a3.x) * dinv,
                             (a0.y + a1.y + a2.y + a3.y) * dinv,
                             (a0.z + a1.z + a2.z + a3.z) * dinv,
                             (a0.w + a1.w + a2.w + a3.w) * dinv);

    if (resid) {
        ushort4 rh = *reinterpret_cast<const ushort4*>(resid + (size_t)node * FDIM + lane * 4);
        acc.x += bf2f(rh.x);
        acc.y += bf2f(rh.y);
        acc.z += bf2f(rh.z);
        acc.w += bf2f(rh.w);
    }
    acc.x = acc.x > 0.f ? acc.x : expm1f(acc.x);
    acc.y = acc.y > 0.f ? acc.y : expm1f(acc.y);
    acc.z = acc.z > 0.f ? acc.z : expm1f(acc.z);
    acc.w = acc.w > 0.f ? acc.w : expm1f(acc.w);

    if (outf) {
        *reinterpret_cast<float4*>(outf + (size_t)node * FDIM + lane * 4) = acc;
    } else {
        *reinterpret_cast<ushort4*>(outh + (size_t)node * FDIM + lane * 4) =
            make_ushort4((ushort)f2bf_rne(acc.x), (ushort)f2bf_rne(acc.y),
                         (ushort)f2bf_rne(acc.z), (ushort)f2bf_rne(acc.w));
    }
}

// ---------------- launch ----------------
extern "C" void kernel_launch(void* const* d_in, const int* in_sizes, int n_in,
                              void* d_out, int out_size, void* d_ws, size_t ws_size,
                              hipStream_t stream) {
    const float* features = (const float*)d_in[0];
    const int*   src      = (const int*)d_in[1];
    const int*   dst      = (const int*)d_in[2];
    const float* W1       = (const float*)d_in[3];
    const float* al1      = (const float*)d_in[4];
    const float* ar1      = (const float*)d_in[5];
    const float* W2       = (const float*)d_in[6];
    const float* al2      = (const float*)d_in[7];
    const float* ar2      = (const float*)d_in[8];
    float* out = (float*)d_out;

    const int N = N_NODES, E = N_EDGES;

    char* ws = (char*)d_ws;
    size_t off = 0;
    auto alloc = [&](size_t bytes) -> void* {
        void* p = ws + off;
        off = (off + bytes + 255) & ~(size_t)255;
        return p;
    };
    ushort* featb  = (ushort*)alloc((size_t)N * FDIM * 2);
    ushort* Afh    = (ushort*)alloc((size_t)N * FDIM * 2);   // layer-1 output (agg1 out, bf16)
    float*  el     = (float*)alloc((size_t)N * NHEAD * 4);
    float*  er     = (float*)alloc((size_t)N * NHEAD * 4);
    int*    rowptr = (int*)alloc((size_t)(N + 1) * 4);
    int*    cnt    = (int*)alloc((size_t)N * 4);
    int*    cursor = (int*)alloc((size_t)N * 4);
    int*    partial= (int*)alloc((size_t)N * 4);
    int*    bsum   = (int*)alloc((size_t)NSCAN * 4);
    int*    srcs   = (int*)alloc((size_t)E * 4);
    ushort* Bt1    = (ushort*)alloc((size_t)256 * 256 * 2);
    ushort* Bt2    = (ushort*)alloc((size_t)256 * 256 * 2);

    const int egrid = (E + 255) / 256;
    const int ngrid4 = (N + 3) / 4;

    // ---- CSR build (by dst) ----
    hipMemsetAsync(cnt, 0, (size_t)N * 4, stream);
    degree_kernel<<<egrid, 256, 0, stream>>>(dst, cnt, E);
    scan1_kernel<<<NSCAN, SCANB, 0, stream>>>(cnt, partial, bsum, N);
    scan3_kernel<<<NSCAN, SCANB, 0, stream>>>(partial, bsum, rowptr, cursor, N);
    scatter_kernel<<<egrid, 256, 0, stream>>>(src, dst, cursor, srcs, E);

    // ---- W conversion for both layers (one dispatch) ----
    bconv_kernel<<<dim3(16, 2), 256, 0, stream>>>(W1, W2, Bt1, Bt2);

    const int ggrid = (N + 127) / 128;

    // ---- layer 1 (A = fp32 features, rounded inline; el/er fused in epilogue) ----
    gemm_mfma_kernel<1><<<ggrid, 512, 0, stream>>>(features, nullptr, Bt1, featb,
                                                   al1, ar1, el, er, N);
    agg_kernel<<<ngrid4, 256, 0, stream>>>(featb, el, er, rowptr, srcs,
                                           nullptr, nullptr, Afh, N);

    // ---- layer 2 (A = layer-1 output bf16; residual = same, bf16) ----
    gemm_mfma_kernel<0><<<ggrid, 512, 0, stream>>>(nullptr, Afh, Bt2, featb,
                                                   al2, ar2, el, er, N);
    agg_kernel<<<ngrid4, 256, 0, stream>>>(featb, el, er, rowptr, srcs,
                                           Afh, out, nullptr, N);
}